// Round 1
// baseline (1525.378 us; speedup 1.0000x reference)
//
#include <hip/hip_runtime.h>
#include <hip/hip_bf16.h>
#include <math.h>

#define NNODES 100000
#define NEDGES 1600000
#define FIN 256
#define HDIM 128
#define NGRAPH 128
#define NCLS 10
#define NEG 0.2f

__device__ __forceinline__ float lrelu(float x) { return x > 0.f ? x : NEG * x; }

// ---------------- GEMM: C[M x 128] = relu?(A[M x K] @ B[K x 128] + bias?) ----
// block: 128 threads, 32 rows x 128 cols tile; per-thread 8 rows x 4 cols.
__global__ __launch_bounds__(128) void gemm128(const float* __restrict__ A,
                                               const float* __restrict__ B,
                                               const float* __restrict__ bias,
                                               float* __restrict__ C,
                                               int M, int K, int dorelu) {
  __shared__ float As[32 * 64];
  int tid = threadIdx.x;
  int row0 = blockIdx.x * 32;
  int cg = (tid & 31) * 4;   // 4 output columns
  int rs = (tid >> 5) * 8;   // 8 output rows within tile
  float acc[8][4];
#pragma unroll
  for (int r = 0; r < 8; ++r)
#pragma unroll
    for (int c = 0; c < 4; ++c) acc[r][c] = 0.f;

  for (int kb = 0; kb < K; kb += 64) {
    __syncthreads();
#pragma unroll
    for (int t = 0; t < 4; ++t) {
      int e = (tid + 128 * t) * 4;       // float offset in 32x64 tile
      int r = e >> 6, kk = e & 63;
      *reinterpret_cast<float4*>(&As[r * 64 + kk]) =
          *reinterpret_cast<const float4*>(&A[(size_t)(row0 + r) * K + kb + kk]);
    }
    __syncthreads();
    for (int kk = 0; kk < 64; kk += 4) {
      float4 a[8];
#pragma unroll
      for (int r = 0; r < 8; ++r)
        a[r] = *reinterpret_cast<const float4*>(&As[(rs + r) * 64 + kk]);
#pragma unroll
      for (int dk = 0; dk < 4; ++dk) {
        float4 b = *reinterpret_cast<const float4*>(&B[(size_t)(kb + kk + dk) * 128 + cg]);
#pragma unroll
        for (int r = 0; r < 8; ++r) {
          float av = dk == 0 ? a[r].x : dk == 1 ? a[r].y : dk == 2 ? a[r].z : a[r].w;
          acc[r][0] = fmaf(av, b.x, acc[r][0]);
          acc[r][1] = fmaf(av, b.y, acc[r][1]);
          acc[r][2] = fmaf(av, b.z, acc[r][2]);
          acc[r][3] = fmaf(av, b.w, acc[r][3]);
        }
      }
    }
  }
#pragma unroll
  for (int r = 0; r < 8; ++r) {
    float4 v = make_float4(acc[r][0], acc[r][1], acc[r][2], acc[r][3]);
    if (bias) { v.x += bias[cg]; v.y += bias[cg + 1]; v.z += bias[cg + 2]; v.w += bias[cg + 3]; }
    if (dorelu) {
      v.x = fmaxf(v.x, 0.f); v.y = fmaxf(v.y, 0.f);
      v.z = fmaxf(v.z, 0.f); v.w = fmaxf(v.w, 0.f);
    }
    *reinterpret_cast<float4*>(&C[(size_t)(row0 + rs + r) * 128 + cg]) = v;
  }
}

// ---------------- graph boundaries (batch is sorted) -------------------------
__global__ void find_starts(const int* __restrict__ batch, int* __restrict__ gstart) {
  int g = threadIdx.x;
  if (g > NGRAPH) return;
  if (g == NGRAPH) { gstart[g] = NNODES; return; }
  int lo = 0, hi = NNODES;
  while (lo < hi) { int mid = (lo + hi) >> 1; if (batch[mid] < g) lo = mid + 1; else hi = mid; }
  gstart[g] = lo;
}

// ---------------- CSR build --------------------------------------------------
__global__ __launch_bounds__(256) void edge_hist(const int* __restrict__ dst,
                                                 int* __restrict__ deg) {
  int j = blockIdx.x * 256 + threadIdx.x;
  if (j < NEDGES) atomicAdd(&deg[dst[j]], 1);
}

__global__ __launch_bounds__(256) void scan_block(const int* __restrict__ deg,
                                                  int* __restrict__ incl,
                                                  int* __restrict__ blocksum) {
  __shared__ int s[256];
  int tid = threadIdx.x;
  int i = blockIdx.x * 256 + tid;
  s[tid] = (i < NNODES) ? deg[i] : 0;
  __syncthreads();
  for (int off = 1; off < 256; off <<= 1) {
    int t = (tid >= off) ? s[tid - off] : 0;
    __syncthreads();
    s[tid] += t;
    __syncthreads();
  }
  if (i < NNODES) incl[i] = s[tid];
  if (tid == 255) blocksum[blockIdx.x] = s[255];
}

__global__ void scan_offsets(int* blocksum, int nb) {
  if (threadIdx.x == 0 && blockIdx.x == 0) {
    int run = 0;
    for (int b = 0; b < nb; ++b) { int t = blocksum[b]; blocksum[b] = run; run += t; }
  }
}

__global__ __launch_bounds__(256) void finalize_csr(const int* __restrict__ deg,
                                                    const int* __restrict__ incl,
                                                    const int* __restrict__ blocksum,
                                                    int* __restrict__ row_ptr,
                                                    int* __restrict__ cursor) {
  int i = blockIdx.x * 256 + threadIdx.x;
  if (i >= NNODES) return;
  int tot = incl[i] + blocksum[i >> 8];
  int rp = tot - deg[i];
  row_ptr[i] = rp;
  cursor[i] = rp;
  if (i == NNODES - 1) row_ptr[NNODES] = tot;
}

__global__ __launch_bounds__(256) void edge_scatter(const int* __restrict__ src,
                                                    const int* __restrict__ dst,
                                                    int* __restrict__ cursor,
                                                    int* __restrict__ colv) {
  int j = blockIdx.x * 256 + threadIdx.x;
  if (j < NEDGES) {
    int d = dst[j];
    int pos = atomicAdd(&cursor[d], 1);
    colv[pos] = src[j];
  }
}

// ---------------- per-node attention logits ----------------------------------
__global__ __launch_bounds__(256) void alpha_kernel(const float* __restrict__ hw,
                                                    const float* __restrict__ aw_src,
                                                    const float* __restrict__ aw_dst,
                                                    float* __restrict__ a_s,
                                                    float* __restrict__ a_d) {
  int wid = (blockIdx.x * 256 + threadIdx.x) >> 6;
  int lane = threadIdx.x & 63;
  if (wid >= NNODES) return;
  float v0 = hw[(size_t)wid * 128 + lane];
  float v1 = hw[(size_t)wid * 128 + 64 + lane];
  float s0 = v0 * aw_src[lane], s1 = v1 * aw_src[64 + lane];
  float d0 = v0 * aw_dst[lane], d1 = v1 * aw_dst[64 + lane];
  for (int o = 32; o; o >>= 1) {
    s0 += __shfl_xor(s0, o); s1 += __shfl_xor(s1, o);
    d0 += __shfl_xor(d0, o); d1 += __shfl_xor(d1, o);
  }
  if (lane == 0) {
    a_s[2 * wid] = s0; a_s[2 * wid + 1] = s1;
    a_d[2 * wid] = d0; a_d[2 * wid + 1] = d1;
  }
}

// ---------------- softmax aggregation: one wave per dst node -----------------
// lane = channel; head0 = chan lane, head1 = chan 64+lane. Self-loop implicit.
// out = relu(agg + bias)  (fused epilogue)
__global__ __launch_bounds__(256) void aggregate(const float* __restrict__ hw,
                                                 const float* __restrict__ a_s,
                                                 const float* __restrict__ a_d,
                                                 const int* __restrict__ row_ptr,
                                                 const int* __restrict__ colv,
                                                 const float* __restrict__ bias,
                                                 float* __restrict__ out) {
  int i = (blockIdx.x * 256 + threadIdx.x) >> 6;
  int lane = threadIdx.x & 63;
  if (i >= NNODES) return;
  float ad0 = a_d[2 * i], ad1 = a_d[2 * i + 1];
  float es0 = lrelu(a_s[2 * i] + ad0), es1 = lrelu(a_s[2 * i + 1] + ad1);  // self edge
  int start = row_ptr[i], end = row_ptr[i + 1];
  int deg = end - start;

  // lane-parallel prefetch of first <=64 edges
  int sl = 0; float a0l = 0.f, a1l = 0.f;
  if (lane < deg) {
    sl = colv[start + lane];
    a0l = a_s[2 * sl]; a1l = a_s[2 * sl + 1];
  }
  // max pass (includes self)
  float m0 = es0, m1 = es1;
  if (lane < deg) {
    m0 = fmaxf(m0, lrelu(a0l + ad0));
    m1 = fmaxf(m1, lrelu(a1l + ad1));
  }
  for (int j = start + 64 + lane; j < end; j += 64) {
    int s = colv[j];
    m0 = fmaxf(m0, lrelu(a_s[2 * s] + ad0));
    m1 = fmaxf(m1, lrelu(a_s[2 * s + 1] + ad1));
  }
  for (int o = 32; o; o >>= 1) {
    m0 = fmaxf(m0, __shfl_xor(m0, o));
    m1 = fmaxf(m1, __shfl_xor(m1, o));
  }

  // accumulate: self first
  float w0 = __expf(es0 - m0), w1 = __expf(es1 - m1);
  float den0 = w0, den1 = w1;
  float acc0 = w0 * hw[(size_t)i * 128 + lane];
  float acc1 = w1 * hw[(size_t)i * 128 + 64 + lane];
  int dmin = deg < 64 ? deg : 64;
  for (int t = 0; t < dmin; ++t) {
    int s = __shfl(sl, t);
    float e0 = lrelu(__shfl(a0l, t) + ad0);
    float e1 = lrelu(__shfl(a1l, t) + ad1);
    w0 = __expf(e0 - m0); w1 = __expf(e1 - m1);
    den0 += w0; den1 += w1;
    acc0 = fmaf(w0, hw[(size_t)s * 128 + lane], acc0);
    acc1 = fmaf(w1, hw[(size_t)s * 128 + 64 + lane], acc1);
  }
  for (int j = start + 64; j < end; ++j) {   // rare overflow path (deg > 64)
    int s = colv[j];
    float e0 = lrelu(a_s[2 * s] + ad0);
    float e1 = lrelu(a_s[2 * s + 1] + ad1);
    w0 = __expf(e0 - m0); w1 = __expf(e1 - m1);
    den0 += w0; den1 += w1;
    acc0 = fmaf(w0, hw[(size_t)s * 128 + lane], acc0);
    acc1 = fmaf(w1, hw[(size_t)s * 128 + 64 + lane], acc1);
  }
  out[(size_t)i * 128 + lane]      = fmaxf(acc0 / den0 + bias[lane], 0.f);
  out[(size_t)i * 128 + 64 + lane] = fmaxf(acc1 / den1 + bias[64 + lane], 0.f);
}

// ---------------- per-graph pooling (batch sorted -> contiguous ranges) ------
__global__ __launch_bounds__(128) void seg_sum(const float* __restrict__ h,
                                               const int* __restrict__ gstart,
                                               float* __restrict__ reprs, int accum) {
  int g = blockIdx.x, tid = threadIdx.x;
  float acc = 0.f;
  int e = gstart[g + 1];
  for (int r = gstart[g]; r < e; ++r) acc += h[(size_t)r * 128 + tid];
  if (accum) reprs[g * 128 + tid] += acc;
  else       reprs[g * 128 + tid] = acc;
}

// ---------------- head MLP + log_softmax -------------------------------------
__global__ __launch_bounds__(128) void head_kernel(const float* __restrict__ reprs,
                                                   const float* __restrict__ pw1,
                                                   const float* __restrict__ pb1,
                                                   const float* __restrict__ pw2,
                                                   const float* __restrict__ pb2,
                                                   float* __restrict__ out) {
  __shared__ float r[128], t1[128], z[NCLS];
  int g = blockIdx.x, tid = threadIdx.x;
  r[tid] = reprs[g * 128 + tid];
  __syncthreads();
  float acc = pb1[tid];
  for (int k = 0; k < 128; ++k) acc = fmaf(r[k], pw1[k * 128 + tid], acc);
  t1[tid] = fmaxf(acc, 0.f);
  __syncthreads();
  if (tid < NCLS) {
    float zz = pb2[tid];
    for (int k = 0; k < 128; ++k) zz = fmaf(t1[k], pw2[k * NCLS + tid], zz);
    z[tid] = zz;
  }
  __syncthreads();
  if (tid == 0) {
    float mx = -1e30f;
    for (int c = 0; c < NCLS; ++c) mx = fmaxf(mx, z[c]);
    float s = 0.f;
    for (int c = 0; c < NCLS; ++c) s += expf(z[c] - mx);
    float ls = logf(s) + mx;
    for (int c = 0; c < NCLS; ++c) out[g * NCLS + c] = z[c] - ls;
  }
}

extern "C" void kernel_launch(void* const* d_in, const int* in_sizes, int n_in,
                              void* d_out, int out_size, void* d_ws, size_t ws_size,
                              hipStream_t stream) {
  const float* x     = (const float*)d_in[0];
  const int*   eidx  = (const int*)d_in[1];
  const int*   batch = (const int*)d_in[2];
  const float* pre_w = (const float*)d_in[3];
  const float* pre_b = (const float*)d_in[4];
  const float* w1    = (const float*)d_in[5];
  const float* asrc1 = (const float*)d_in[6];
  const float* adst1 = (const float*)d_in[7];
  const float* b1    = (const float*)d_in[8];
  const float* w2    = (const float*)d_in[9];
  const float* asrc2 = (const float*)d_in[10];
  const float* adst2 = (const float*)d_in[11];
  const float* b2    = (const float*)d_in[12];
  const float* pw1   = (const float*)d_in[13];
  const float* pb1   = (const float*)d_in[14];
  const float* pw2   = (const float*)d_in[15];
  const float* pb2   = (const float*)d_in[16];
  float* out = (float*)d_out;

  const int* esrc = eidx;
  const int* edst = eidx + NEDGES;

  char* wsp = (char*)d_ws;
  size_t off = 0;
  auto alloc = [&](size_t bytes) -> void* {
    void* p = wsp + off;
    off += (bytes + 255) & ~(size_t)255;
    return p;
  };
  float* h       = (float*)alloc((size_t)NNODES * 128 * 4);
  float* hw      = (float*)alloc((size_t)NNODES * 128 * 4);
  float* a_s     = (float*)alloc((size_t)NNODES * 2 * 4);
  float* a_d     = (float*)alloc((size_t)NNODES * 2 * 4);
  float* reprs   = (float*)alloc((size_t)NGRAPH * 128 * 4);
  int* gstart    = (int*)alloc((NGRAPH + 1) * 4);
  int* deg       = (int*)alloc((size_t)NNODES * 4);
  int* incl      = (int*)alloc((size_t)NNODES * 4);
  int* row_ptr   = (int*)alloc(((size_t)NNODES + 1) * 4);
  int* cursor    = (int*)alloc((size_t)NNODES * 4);
  int* colv      = (int*)alloc((size_t)NEDGES * 4);
  int* blocksum  = (int*)alloc(512 * 4);

  int nb = (NNODES + 255) / 256;   // 391
  int eb = (NEDGES + 255) / 256;   // 6250
  int wb = NNODES / 4;             // wave-per-node kernels: 256 thr = 4 waves

  // CSR build + graph boundaries
  hipMemsetAsync(deg, 0, (size_t)NNODES * 4, stream);
  find_starts<<<1, 256, 0, stream>>>(batch, gstart);
  edge_hist<<<eb, 256, 0, stream>>>(edst, deg);
  scan_block<<<nb, 256, 0, stream>>>(deg, incl, blocksum);
  scan_offsets<<<1, 64, 0, stream>>>(blocksum, nb);
  finalize_csr<<<nb, 256, 0, stream>>>(deg, incl, blocksum, row_ptr, cursor);
  edge_scatter<<<eb, 256, 0, stream>>>(esrc, edst, cursor, colv);

  // pre layer: h0 = relu(x @ pre_w + pre_b)
  gemm128<<<NNODES / 32, 128, 0, stream>>>(x, pre_w, pre_b, h, NNODES, FIN, 1);
  seg_sum<<<NGRAPH, 128, 0, stream>>>(h, gstart, reprs, 0);

  // GAT layer 1
  gemm128<<<NNODES / 32, 128, 0, stream>>>(h, w1, nullptr, hw, NNODES, HDIM, 0);
  alpha_kernel<<<wb, 256, 0, stream>>>(hw, asrc1, adst1, a_s, a_d);
  aggregate<<<wb, 256, 0, stream>>>(hw, a_s, a_d, row_ptr, colv, b1, h);
  seg_sum<<<NGRAPH, 128, 0, stream>>>(h, gstart, reprs, 1);

  // GAT layer 2
  gemm128<<<NNODES / 32, 128, 0, stream>>>(h, w2, nullptr, hw, NNODES, HDIM, 0);
  alpha_kernel<<<wb, 256, 0, stream>>>(hw, asrc2, adst2, a_s, a_d);
  aggregate<<<wb, 256, 0, stream>>>(hw, a_s, a_d, row_ptr, colv, b2, h);
  seg_sum<<<NGRAPH, 128, 0, stream>>>(h, gstart, reprs, 1);

  // head
  head_kernel<<<NGRAPH, 128, 0, stream>>>(reprs, pw1, pb1, pw2, pb2, out);
}

// Round 2
// 1109.752 us; speedup vs baseline: 1.3745x; 1.3745x over previous
//
#include <hip/hip_runtime.h>
#include <hip/hip_bf16.h>
#include <math.h>

#define NNODES 100000
#define NEDGES 1600000
#define FIN 256
#define HDIM 128
#define NGRAPH 128
#define NCLS 10
#define NEG 0.2f

__device__ __forceinline__ float lrelu(float x) { return x > 0.f ? x : NEG * x; }

// ---------------- GEMM: C[M x 128] = relu?(A[M x K] @ B[K x 128] + bias?) ----
// block: 128 threads, 32 rows x 128 cols tile; per-thread 8 rows x 4 cols.
__global__ __launch_bounds__(128) void gemm128(const float* __restrict__ A,
                                               const float* __restrict__ B,
                                               const float* __restrict__ bias,
                                               float* __restrict__ C,
                                               int M, int K, int dorelu) {
  __shared__ float As[32 * 64];
  int tid = threadIdx.x;
  int row0 = blockIdx.x * 32;
  int cg = (tid & 31) * 4;   // 4 output columns
  int rs = (tid >> 5) * 8;   // 8 output rows within tile
  float acc[8][4];
#pragma unroll
  for (int r = 0; r < 8; ++r)
#pragma unroll
    for (int c = 0; c < 4; ++c) acc[r][c] = 0.f;

  for (int kb = 0; kb < K; kb += 64) {
    __syncthreads();
#pragma unroll
    for (int t = 0; t < 4; ++t) {
      int e = (tid + 128 * t) * 4;       // float offset in 32x64 tile
      int r = e >> 6, kk = e & 63;
      *reinterpret_cast<float4*>(&As[r * 64 + kk]) =
          *reinterpret_cast<const float4*>(&A[(size_t)(row0 + r) * K + kb + kk]);
    }
    __syncthreads();
    for (int kk = 0; kk < 64; kk += 4) {
      float4 a[8];
#pragma unroll
      for (int r = 0; r < 8; ++r)
        a[r] = *reinterpret_cast<const float4*>(&As[(rs + r) * 64 + kk]);
#pragma unroll
      for (int dk = 0; dk < 4; ++dk) {
        float4 b = *reinterpret_cast<const float4*>(&B[(size_t)(kb + kk + dk) * 128 + cg]);
#pragma unroll
        for (int r = 0; r < 8; ++r) {
          float av = dk == 0 ? a[r].x : dk == 1 ? a[r].y : dk == 2 ? a[r].z : a[r].w;
          acc[r][0] = fmaf(av, b.x, acc[r][0]);
          acc[r][1] = fmaf(av, b.y, acc[r][1]);
          acc[r][2] = fmaf(av, b.z, acc[r][2]);
          acc[r][3] = fmaf(av, b.w, acc[r][3]);
        }
      }
    }
  }
#pragma unroll
  for (int r = 0; r < 8; ++r) {
    float4 v = make_float4(acc[r][0], acc[r][1], acc[r][2], acc[r][3]);
    if (bias) { v.x += bias[cg]; v.y += bias[cg + 1]; v.z += bias[cg + 2]; v.w += bias[cg + 3]; }
    if (dorelu) {
      v.x = fmaxf(v.x, 0.f); v.y = fmaxf(v.y, 0.f);
      v.z = fmaxf(v.z, 0.f); v.w = fmaxf(v.w, 0.f);
    }
    *reinterpret_cast<float4*>(&C[(size_t)(row0 + rs + r) * 128 + cg]) = v;
  }
}

// ---------------- graph boundaries (batch is sorted) -------------------------
__global__ void find_starts(const int* __restrict__ batch, int* __restrict__ gstart) {
  int g = threadIdx.x;
  if (g > NGRAPH) return;
  if (g == NGRAPH) { gstart[g] = NNODES; return; }
  int lo = 0, hi = NNODES;
  while (lo < hi) { int mid = (lo + hi) >> 1; if (batch[mid] < g) lo = mid + 1; else hi = mid; }
  gstart[g] = lo;
}

// ---------------- CSR build --------------------------------------------------
__global__ __launch_bounds__(256) void edge_hist(const int* __restrict__ dst,
                                                 int* __restrict__ deg) {
  int j = blockIdx.x * 256 + threadIdx.x;
  if (j < NEDGES) atomicAdd(&deg[dst[j]], 1);
}

__global__ __launch_bounds__(256) void scan_block(const int* __restrict__ deg,
                                                  int* __restrict__ incl,
                                                  int* __restrict__ blocksum) {
  __shared__ int s[256];
  int tid = threadIdx.x;
  int i = blockIdx.x * 256 + tid;
  s[tid] = (i < NNODES) ? deg[i] : 0;
  __syncthreads();
  for (int off = 1; off < 256; off <<= 1) {
    int t = (tid >= off) ? s[tid - off] : 0;
    __syncthreads();
    s[tid] += t;
    __syncthreads();
  }
  if (i < NNODES) incl[i] = s[tid];
  if (tid == 255) blocksum[blockIdx.x] = s[255];
}

__global__ void scan_offsets(int* blocksum, int nb) {
  if (threadIdx.x == 0 && blockIdx.x == 0) {
    int run = 0;
    for (int b = 0; b < nb; ++b) { int t = blocksum[b]; blocksum[b] = run; run += t; }
  }
}

__global__ __launch_bounds__(256) void finalize_csr(const int* __restrict__ deg,
                                                    const int* __restrict__ incl,
                                                    const int* __restrict__ blocksum,
                                                    int* __restrict__ row_ptr,
                                                    int* __restrict__ cursor) {
  int i = blockIdx.x * 256 + threadIdx.x;
  if (i >= NNODES) return;
  int tot = incl[i] + blocksum[i >> 8];
  int rp = tot - deg[i];
  row_ptr[i] = rp;
  cursor[i] = rp;
  if (i == NNODES - 1) row_ptr[NNODES] = tot;
}

__global__ __launch_bounds__(256) void edge_scatter(const int* __restrict__ src,
                                                    const int* __restrict__ dst,
                                                    int* __restrict__ cursor,
                                                    int* __restrict__ colv) {
  int j = blockIdx.x * 256 + threadIdx.x;
  if (j < NEDGES) {
    int d = dst[j];
    int pos = atomicAdd(&cursor[d], 1);
    colv[pos] = src[j];
  }
}

// ---------------- per-node attention logits ----------------------------------
__global__ __launch_bounds__(256) void alpha_kernel(const float* __restrict__ hw,
                                                    const float* __restrict__ aw_src,
                                                    const float* __restrict__ aw_dst,
                                                    float* __restrict__ a_s,
                                                    float* __restrict__ a_d) {
  int wid = (blockIdx.x * 256 + threadIdx.x) >> 6;
  int lane = threadIdx.x & 63;
  if (wid >= NNODES) return;
  float v0 = hw[(size_t)wid * 128 + lane];
  float v1 = hw[(size_t)wid * 128 + 64 + lane];
  float s0 = v0 * aw_src[lane], s1 = v1 * aw_src[64 + lane];
  float d0 = v0 * aw_dst[lane], d1 = v1 * aw_dst[64 + lane];
  for (int o = 32; o; o >>= 1) {
    s0 += __shfl_xor(s0, o); s1 += __shfl_xor(s1, o);
    d0 += __shfl_xor(d0, o); d1 += __shfl_xor(d1, o);
  }
  if (lane == 0) {
    a_s[2 * wid] = s0; a_s[2 * wid + 1] = s1;
    a_d[2 * wid] = d0; a_d[2 * wid + 1] = d1;
  }
}

// ---------------- softmax aggregation: one wave per dst node -----------------
__global__ __launch_bounds__(256) void aggregate(const float* __restrict__ hw,
                                                 const float* __restrict__ a_s,
                                                 const float* __restrict__ a_d,
                                                 const int* __restrict__ row_ptr,
                                                 const int* __restrict__ colv,
                                                 const float* __restrict__ bias,
                                                 float* __restrict__ out) {
  int i = (blockIdx.x * 256 + threadIdx.x) >> 6;
  int lane = threadIdx.x & 63;
  if (i >= NNODES) return;
  float ad0 = a_d[2 * i], ad1 = a_d[2 * i + 1];
  float es0 = lrelu(a_s[2 * i] + ad0), es1 = lrelu(a_s[2 * i + 1] + ad1);  // self edge
  int start = row_ptr[i], end = row_ptr[i + 1];
  int deg = end - start;

  // lane-parallel prefetch of first <=64 edges
  int sl = 0; float a0l = 0.f, a1l = 0.f;
  if (lane < deg) {
    sl = colv[start + lane];
    a0l = a_s[2 * sl]; a1l = a_s[2 * sl + 1];
  }
  // max pass (includes self)
  float m0 = es0, m1 = es1;
  if (lane < deg) {
    m0 = fmaxf(m0, lrelu(a0l + ad0));
    m1 = fmaxf(m1, lrelu(a1l + ad1));
  }
  for (int j = start + 64 + lane; j < end; j += 64) {
    int s = colv[j];
    m0 = fmaxf(m0, lrelu(a_s[2 * s] + ad0));
    m1 = fmaxf(m1, lrelu(a_s[2 * s + 1] + ad1));
  }
  for (int o = 32; o; o >>= 1) {
    m0 = fmaxf(m0, __shfl_xor(m0, o));
    m1 = fmaxf(m1, __shfl_xor(m1, o));
  }

  // accumulate: self first
  float w0 = __expf(es0 - m0), w1 = __expf(es1 - m1);
  float den0 = w0, den1 = w1;
  float acc0 = w0 * hw[(size_t)i * 128 + lane];
  float acc1 = w1 * hw[(size_t)i * 128 + 64 + lane];
  int dmin = deg < 64 ? deg : 64;
  for (int t = 0; t < dmin; ++t) {
    int s = __shfl(sl, t);
    float e0 = lrelu(__shfl(a0l, t) + ad0);
    float e1 = lrelu(__shfl(a1l, t) + ad1);
    w0 = __expf(e0 - m0); w1 = __expf(e1 - m1);
    den0 += w0; den1 += w1;
    acc0 = fmaf(w0, hw[(size_t)s * 128 + lane], acc0);
    acc1 = fmaf(w1, hw[(size_t)s * 128 + 64 + lane], acc1);
  }
  for (int j = start + 64; j < end; ++j) {   // rare overflow path (deg > 64)
    int s = colv[j];
    float e0 = lrelu(a_s[2 * s] + ad0);
    float e1 = lrelu(a_s[2 * s + 1] + ad1);
    w0 = __expf(e0 - m0); w1 = __expf(e1 - m1);
    den0 += w0; den1 += w1;
    acc0 = fmaf(w0, hw[(size_t)s * 128 + lane], acc0);
    acc1 = fmaf(w1, hw[(size_t)s * 128 + 64 + lane], acc1);
  }
  out[(size_t)i * 128 + lane]      = fmaxf(acc0 / den0 + bias[lane], 0.f);
  out[(size_t)i * 128 + 64 + lane] = fmaxf(acc1 / den1 + bias[64 + lane], 0.f);
}

// ---------------- per-graph pooling, node-parallel ---------------------------
// 391 blocks x 128 threads; each block walks a 256-node chunk. batch sorted ->
// chunk spans few graph segments; branch-free inner loop per segment, then one
// atomicAdd per (segment, channel). reprs must be zeroed before first call.
#define SEG_CHUNK 256
__global__ __launch_bounds__(128) void seg_sum_fast(const float* __restrict__ h,
                                                    const int* __restrict__ batch,
                                                    const int* __restrict__ gstart,
                                                    float* __restrict__ reprs) {
  int n0 = blockIdx.x * SEG_CHUNK;
  if (n0 >= NNODES) return;
  int nend = n0 + SEG_CHUNK; if (nend > NNODES) nend = NNODES;
  int tid = threadIdx.x;
  int r = n0;
  while (r < nend) {
    int g = batch[r];
    int segend = gstart[g + 1]; if (segend > nend) segend = nend;
    float acc = 0.f;
    for (; r < segend; ++r) acc += h[(size_t)r * 128 + tid];
    atomicAdd(&reprs[g * 128 + tid], acc);
  }
}

// ---------------- head MLP + log_softmax -------------------------------------
__global__ __launch_bounds__(128) void head_kernel(const float* __restrict__ reprs,
                                                   const float* __restrict__ pw1,
                                                   const float* __restrict__ pb1,
                                                   const float* __restrict__ pw2,
                                                   const float* __restrict__ pb2,
                                                   float* __restrict__ out) {
  __shared__ float r[128], t1[128], z[NCLS];
  int g = blockIdx.x, tid = threadIdx.x;
  r[tid] = reprs[g * 128 + tid];
  __syncthreads();
  float acc = pb1[tid];
  for (int k = 0; k < 128; ++k) acc = fmaf(r[k], pw1[k * 128 + tid], acc);
  t1[tid] = fmaxf(acc, 0.f);
  __syncthreads();
  if (tid < NCLS) {
    float zz = pb2[tid];
    for (int k = 0; k < 128; ++k) zz = fmaf(t1[k], pw2[k * NCLS + tid], zz);
    z[tid] = zz;
  }
  __syncthreads();
  if (tid == 0) {
    float mx = -1e30f;
    for (int c = 0; c < NCLS; ++c) mx = fmaxf(mx, z[c]);
    float s = 0.f;
    for (int c = 0; c < NCLS; ++c) s += expf(z[c] - mx);
    float ls = logf(s) + mx;
    for (int c = 0; c < NCLS; ++c) out[g * NCLS + c] = z[c] - ls;
  }
}

extern "C" void kernel_launch(void* const* d_in, const int* in_sizes, int n_in,
                              void* d_out, int out_size, void* d_ws, size_t ws_size,
                              hipStream_t stream) {
  const float* x     = (const float*)d_in[0];
  const int*   eidx  = (const int*)d_in[1];
  const int*   batch = (const int*)d_in[2];
  const float* pre_w = (const float*)d_in[3];
  const float* pre_b = (const float*)d_in[4];
  const float* w1    = (const float*)d_in[5];
  const float* asrc1 = (const float*)d_in[6];
  const float* adst1 = (const float*)d_in[7];
  const float* b1    = (const float*)d_in[8];
  const float* w2    = (const float*)d_in[9];
  const float* asrc2 = (const float*)d_in[10];
  const float* adst2 = (const float*)d_in[11];
  const float* b2    = (const float*)d_in[12];
  const float* pw1   = (const float*)d_in[13];
  const float* pb1   = (const float*)d_in[14];
  const float* pw2   = (const float*)d_in[15];
  const float* pb2   = (const float*)d_in[16];
  float* out = (float*)d_out;

  const int* esrc = eidx;
  const int* edst = eidx + NEDGES;

  char* wsp = (char*)d_ws;
  size_t off = 0;
  auto alloc = [&](size_t bytes) -> void* {
    void* p = wsp + off;
    off += (bytes + 255) & ~(size_t)255;
    return p;
  };
  float* h       = (float*)alloc((size_t)NNODES * 128 * 4);
  float* hw      = (float*)alloc((size_t)NNODES * 128 * 4);
  float* a_s     = (float*)alloc((size_t)NNODES * 2 * 4);
  float* a_d     = (float*)alloc((size_t)NNODES * 2 * 4);
  float* reprs   = (float*)alloc((size_t)NGRAPH * 128 * 4);
  int* gstart    = (int*)alloc((NGRAPH + 1) * 4);
  int* deg       = (int*)alloc((size_t)NNODES * 4);
  int* incl      = (int*)alloc((size_t)NNODES * 4);
  int* row_ptr   = (int*)alloc(((size_t)NNODES + 1) * 4);
  int* cursor    = (int*)alloc((size_t)NNODES * 4);
  int* colv      = (int*)alloc((size_t)NEDGES * 4);
  int* blocksum  = (int*)alloc(512 * 4);

  int nb = (NNODES + 255) / 256;   // 391
  int eb = (NEDGES + 255) / 256;   // 6250
  int wb = NNODES / 4;             // wave-per-node kernels: 256 thr = 4 waves
  int sb = (NNODES + SEG_CHUNK - 1) / SEG_CHUNK;

  // CSR build + graph boundaries
  hipMemsetAsync(deg, 0, (size_t)NNODES * 4, stream);
  hipMemsetAsync(reprs, 0, (size_t)NGRAPH * 128 * 4, stream);
  find_starts<<<1, 256, 0, stream>>>(batch, gstart);
  edge_hist<<<eb, 256, 0, stream>>>(edst, deg);
  scan_block<<<nb, 256, 0, stream>>>(deg, incl, blocksum);
  scan_offsets<<<1, 64, 0, stream>>>(blocksum, nb);
  finalize_csr<<<nb, 256, 0, stream>>>(deg, incl, blocksum, row_ptr, cursor);
  edge_scatter<<<eb, 256, 0, stream>>>(esrc, edst, cursor, colv);

  // pre layer: h0 = relu(x @ pre_w + pre_b)
  gemm128<<<NNODES / 32, 128, 0, stream>>>(x, pre_w, pre_b, h, NNODES, FIN, 1);
  seg_sum_fast<<<sb, 128, 0, stream>>>(h, batch, gstart, reprs);

  // GAT layer 1
  gemm128<<<NNODES / 32, 128, 0, stream>>>(h, w1, nullptr, hw, NNODES, HDIM, 0);
  alpha_kernel<<<wb, 256, 0, stream>>>(hw, asrc1, adst1, a_s, a_d);
  aggregate<<<wb, 256, 0, stream>>>(hw, a_s, a_d, row_ptr, colv, b1, h);
  seg_sum_fast<<<sb, 128, 0, stream>>>(h, batch, gstart, reprs);

  // GAT layer 2
  gemm128<<<NNODES / 32, 128, 0, stream>>>(h, w2, nullptr, hw, NNODES, HDIM, 0);
  alpha_kernel<<<wb, 256, 0, stream>>>(hw, asrc2, adst2, a_s, a_d);
  aggregate<<<wb, 256, 0, stream>>>(hw, a_s, a_d, row_ptr, colv, b2, h);
  seg_sum_fast<<<sb, 128, 0, stream>>>(h, batch, gstart, reprs);

  // head
  head_kernel<<<NGRAPH, 128, 0, stream>>>(reprs, pw1, pb1, pw2, pb2, out);
}

// Round 3
// 984.091 us; speedup vs baseline: 1.5500x; 1.1277x over previous
//
#include <hip/hip_runtime.h>
#include <hip/hip_bf16.h>
#include <math.h>

#define NNODES 100000
#define NEDGES 1600000
#define FIN 256
#define HDIM 128
#define NGRAPH 128
#define NCLS 10
#define NEG 0.2f

__device__ __forceinline__ float lrelu(float x) { return x > 0.f ? x : NEG * x; }

__device__ __forceinline__ unsigned short f2bf(float f) {
  union { float f; unsigned int u; } v; v.f = f;
  unsigned int r = v.u + 0x7fffu + ((v.u >> 16) & 1u);   // round-nearest-even
  return (unsigned short)(r >> 16);
}
__device__ __forceinline__ float bf_lo(unsigned int p) {
  union { unsigned int u; float f; } v; v.u = p << 16; return v.f;
}
__device__ __forceinline__ float bf_hi(unsigned int p) {
  union { unsigned int u; float f; } v; v.u = p & 0xffff0000u; return v.f;
}

// ---------------- GEMM: [M x 128] = A[M x K] @ B[K x 128] (+bias, relu) ------
// block: 128 threads, 32-row tile; per-thread cols {c0, c0+1, c0+64, c0+65},
// 8 rows. Output either fp32 C, or packed bf16 Cp: ushort2{head0,head1} per
// channel (Cp[row*64 + chan]).
__global__ __launch_bounds__(128) void gemm128(const float* __restrict__ A,
                                               const float* __restrict__ B,
                                               const float* __restrict__ bias,
                                               float* __restrict__ C,
                                               unsigned int* __restrict__ Cp,
                                               int M, int K, int dorelu) {
  __shared__ float As[32 * 64];
  int tid = threadIdx.x;
  int row0 = blockIdx.x * 32;
  int c0 = (tid & 31) * 2;
  int rs = (tid >> 5) * 8;
  float acc[8][4];
#pragma unroll
  for (int r = 0; r < 8; ++r)
#pragma unroll
    for (int c = 0; c < 4; ++c) acc[r][c] = 0.f;

  for (int kb = 0; kb < K; kb += 64) {
    __syncthreads();
#pragma unroll
    for (int t = 0; t < 4; ++t) {
      int e = (tid + 128 * t) * 4;
      int r = e >> 6, kk = e & 63;
      *reinterpret_cast<float4*>(&As[r * 64 + kk]) =
          *reinterpret_cast<const float4*>(&A[(size_t)(row0 + r) * K + kb + kk]);
    }
    __syncthreads();
    for (int kk = 0; kk < 64; kk += 4) {
      float4 a[8];
#pragma unroll
      for (int r = 0; r < 8; ++r)
        a[r] = *reinterpret_cast<const float4*>(&As[(rs + r) * 64 + kk]);
#pragma unroll
      for (int dk = 0; dk < 4; ++dk) {
        const float* brow = &B[(size_t)(kb + kk + dk) * 128];
        float2 blo = *reinterpret_cast<const float2*>(&brow[c0]);
        float2 bhi = *reinterpret_cast<const float2*>(&brow[c0 + 64]);
#pragma unroll
        for (int r = 0; r < 8; ++r) {
          float av = dk == 0 ? a[r].x : dk == 1 ? a[r].y : dk == 2 ? a[r].z : a[r].w;
          acc[r][0] = fmaf(av, blo.x, acc[r][0]);
          acc[r][1] = fmaf(av, blo.y, acc[r][1]);
          acc[r][2] = fmaf(av, bhi.x, acc[r][2]);
          acc[r][3] = fmaf(av, bhi.y, acc[r][3]);
        }
      }
    }
  }
  if (Cp) {
#pragma unroll
    for (int r = 0; r < 8; ++r) {
      unsigned int p0 = (unsigned int)f2bf(acc[r][0]) | ((unsigned int)f2bf(acc[r][2]) << 16);
      unsigned int p1 = (unsigned int)f2bf(acc[r][1]) | ((unsigned int)f2bf(acc[r][3]) << 16);
      *reinterpret_cast<uint2*>(&Cp[(size_t)(row0 + rs + r) * 64 + c0]) = make_uint2(p0, p1);
    }
  } else {
#pragma unroll
    for (int r = 0; r < 8; ++r) {
      float2 vlo = make_float2(acc[r][0], acc[r][1]);
      float2 vhi = make_float2(acc[r][2], acc[r][3]);
      if (bias) {
        vlo.x += bias[c0]; vlo.y += bias[c0 + 1];
        vhi.x += bias[c0 + 64]; vhi.y += bias[c0 + 65];
      }
      if (dorelu) {
        vlo.x = fmaxf(vlo.x, 0.f); vlo.y = fmaxf(vlo.y, 0.f);
        vhi.x = fmaxf(vhi.x, 0.f); vhi.y = fmaxf(vhi.y, 0.f);
      }
      float* crow = &C[(size_t)(row0 + rs + r) * 128];
      *reinterpret_cast<float2*>(&crow[c0]) = vlo;
      *reinterpret_cast<float2*>(&crow[c0 + 64]) = vhi;
    }
  }
}

// ---------------- graph boundaries (batch is sorted) -------------------------
__global__ void find_starts(const int* __restrict__ batch, int* __restrict__ gstart) {
  int g = threadIdx.x;
  if (g > NGRAPH) return;
  if (g == NGRAPH) { gstart[g] = NNODES; return; }
  int lo = 0, hi = NNODES;
  while (lo < hi) { int mid = (lo + hi) >> 1; if (batch[mid] < g) lo = mid + 1; else hi = mid; }
  gstart[g] = lo;
}

// ---------------- CSR build --------------------------------------------------
__global__ __launch_bounds__(256) void edge_hist(const int* __restrict__ dst,
                                                 int* __restrict__ deg) {
  int j = blockIdx.x * 256 + threadIdx.x;
  if (j < NEDGES) atomicAdd(&deg[dst[j]], 1);
}

__global__ __launch_bounds__(256) void scan_block(const int* __restrict__ deg,
                                                  int* __restrict__ incl,
                                                  int* __restrict__ blocksum) {
  __shared__ int s[256];
  int tid = threadIdx.x;
  int i = blockIdx.x * 256 + tid;
  s[tid] = (i < NNODES) ? deg[i] : 0;
  __syncthreads();
  for (int off = 1; off < 256; off <<= 1) {
    int t = (tid >= off) ? s[tid - off] : 0;
    __syncthreads();
    s[tid] += t;
    __syncthreads();
  }
  if (i < NNODES) incl[i] = s[tid];
  if (tid == 255) blocksum[blockIdx.x] = s[255];
}

__global__ void scan_offsets(int* blocksum, int nb) {
  if (threadIdx.x == 0 && blockIdx.x == 0) {
    int run = 0;
    for (int b = 0; b < nb; ++b) { int t = blocksum[b]; blocksum[b] = run; run += t; }
  }
}

__global__ __launch_bounds__(256) void finalize_csr(const int* __restrict__ deg,
                                                    const int* __restrict__ incl,
                                                    const int* __restrict__ blocksum,
                                                    int* __restrict__ row_ptr,
                                                    int* __restrict__ cursor) {
  int i = blockIdx.x * 256 + threadIdx.x;
  if (i >= NNODES) return;
  int tot = incl[i] + blocksum[i >> 8];
  int rp = tot - deg[i];
  row_ptr[i] = rp;
  cursor[i] = rp;
  if (i == NNODES - 1) row_ptr[NNODES] = tot;
}

__global__ __launch_bounds__(256) void edge_scatter(const int* __restrict__ src,
                                                    const int* __restrict__ dst,
                                                    int* __restrict__ cursor,
                                                    int* __restrict__ colv) {
  int j = blockIdx.x * 256 + threadIdx.x;
  if (j < NEDGES) {
    int d = dst[j];
    int pos = atomicAdd(&cursor[d], 1);
    colv[pos] = src[j];
  }
}

// ---------------- per-node attention logits (packed bf16 input) --------------
__global__ __launch_bounds__(256) void alpha_kernel(const unsigned int* __restrict__ hwb,
                                                    const float* __restrict__ aw_src,
                                                    const float* __restrict__ aw_dst,
                                                    float* __restrict__ a_s,
                                                    float* __restrict__ a_d) {
  int wid = (blockIdx.x * 256 + threadIdx.x) >> 6;
  int lane = threadIdx.x & 63;
  if (wid >= NNODES) return;
  unsigned int p = hwb[(size_t)wid * 64 + lane];
  float v0 = bf_lo(p), v1 = bf_hi(p);
  float s0 = v0 * aw_src[lane], s1 = v1 * aw_src[64 + lane];
  float d0 = v0 * aw_dst[lane], d1 = v1 * aw_dst[64 + lane];
  for (int o = 32; o; o >>= 1) {
    s0 += __shfl_xor(s0, o); s1 += __shfl_xor(s1, o);
    d0 += __shfl_xor(d0, o); d1 += __shfl_xor(d1, o);
  }
  if (lane == 0) {
    a_s[2 * wid] = s0; a_s[2 * wid + 1] = s1;
    a_d[2 * wid] = d0; a_d[2 * wid + 1] = d1;
  }
}

// ---------------- softmax aggregation: one wave per dst node -----------------
// Weights computed lane-parallel (one exp per lane covers 64 edges), gathered
// features are packed bf16 (one 4B load per lane serves both heads).
__global__ __launch_bounds__(256) void aggregate(const unsigned int* __restrict__ hwb,
                                                 const float* __restrict__ a_s,
                                                 const float* __restrict__ a_d,
                                                 const int* __restrict__ row_ptr,
                                                 const int* __restrict__ colv,
                                                 const float* __restrict__ bias,
                                                 float* __restrict__ out) {
  int i = (blockIdx.x * 256 + threadIdx.x) >> 6;
  int lane = threadIdx.x & 63;
  if (i >= NNODES) return;
  float ad0 = a_d[2 * i], ad1 = a_d[2 * i + 1];
  float es0 = lrelu(a_s[2 * i] + ad0), es1 = lrelu(a_s[2 * i + 1] + ad1);  // self edge
  int start = row_ptr[i], end = row_ptr[i + 1];
  int deg = end - start;

  // lane-parallel logits for first <=64 edges
  int sl = 0; float e0l = -1e30f, e1l = -1e30f;
  if (lane < deg) {
    sl = colv[start + lane];
    float2 av = *reinterpret_cast<const float2*>(&a_s[2 * sl]);
    e0l = lrelu(av.x + ad0); e1l = lrelu(av.y + ad1);
  }
  // max (self + all edges)
  float m0 = fmaxf(es0, e0l), m1 = fmaxf(es1, e1l);
  for (int j = start + 64 + lane; j < end; j += 64) {
    int s = colv[j];
    float2 av = *reinterpret_cast<const float2*>(&a_s[2 * s]);
    m0 = fmaxf(m0, lrelu(av.x + ad0));
    m1 = fmaxf(m1, lrelu(av.y + ad1));
  }
  for (int o = 32; o; o >>= 1) {
    m0 = fmaxf(m0, __shfl_xor(m0, o));
    m1 = fmaxf(m1, __shfl_xor(m1, o));
  }
  // lane-parallel weights + denominator
  float w0l = lane < deg ? __expf(e0l - m0) : 0.f;
  float w1l = lane < deg ? __expf(e1l - m1) : 0.f;
  float d0 = w0l, d1 = w1l;
  for (int o = 32; o; o >>= 1) { d0 += __shfl_xor(d0, o); d1 += __shfl_xor(d1, o); }
  float ws0 = __expf(es0 - m0), ws1 = __expf(es1 - m1);
  float den0 = d0 + ws0, den1 = d1 + ws1;

  // accumulate: self, then broadcast loop (shfl weights, gather packed bf16)
  unsigned int ps = hwb[(size_t)i * 64 + lane];
  float acc0 = ws0 * bf_lo(ps), acc1 = ws1 * bf_hi(ps);
  int dmin = deg < 64 ? deg : 64;
  for (int t = 0; t < dmin; ++t) {
    int s = __shfl(sl, t);
    float w0 = __shfl(w0l, t), w1 = __shfl(w1l, t);
    unsigned int q = hwb[(size_t)s * 64 + lane];
    acc0 = fmaf(w0, bf_lo(q), acc0);
    acc1 = fmaf(w1, bf_hi(q), acc1);
  }
  for (int j = start + 64; j < end; ++j) {   // rare overflow path (deg > 64)
    int s = colv[j];
    float2 av = *reinterpret_cast<const float2*>(&a_s[2 * s]);
    float w0 = __expf(lrelu(av.x + ad0) - m0);
    float w1 = __expf(lrelu(av.y + ad1) - m1);
    den0 += w0; den1 += w1;
    unsigned int q = hwb[(size_t)s * 64 + lane];
    acc0 = fmaf(w0, bf_lo(q), acc0);
    acc1 = fmaf(w1, bf_hi(q), acc1);
  }
  out[(size_t)i * 128 + lane]      = fmaxf(acc0 / den0 + bias[lane], 0.f);
  out[(size_t)i * 128 + 64 + lane] = fmaxf(acc1 / den1 + bias[64 + lane], 0.f);
}

// ---------------- per-graph pooling, node-parallel ---------------------------
#define SEG_CHUNK 128
__global__ __launch_bounds__(128) void seg_sum_fast(const float* __restrict__ h,
                                                    const int* __restrict__ batch,
                                                    const int* __restrict__ gstart,
                                                    float* __restrict__ reprs) {
  int n0 = blockIdx.x * SEG_CHUNK;
  if (n0 >= NNODES) return;
  int nend = n0 + SEG_CHUNK; if (nend > NNODES) nend = NNODES;
  int tid = threadIdx.x;
  int r = n0;
  while (r < nend) {
    int g = batch[r];
    int segend = gstart[g + 1]; if (segend > nend) segend = nend;
    float a0 = 0.f, a1 = 0.f, a2 = 0.f, a3 = 0.f;
    for (; r + 3 < segend; r += 4) {
      a0 += h[(size_t)r * 128 + tid];
      a1 += h[(size_t)(r + 1) * 128 + tid];
      a2 += h[(size_t)(r + 2) * 128 + tid];
      a3 += h[(size_t)(r + 3) * 128 + tid];
    }
    for (; r < segend; ++r) a0 += h[(size_t)r * 128 + tid];
    atomicAdd(&reprs[g * 128 + tid], (a0 + a1) + (a2 + a3));
  }
}

// ---------------- head MLP + log_softmax -------------------------------------
__global__ __launch_bounds__(128) void head_kernel(const float* __restrict__ reprs,
                                                   const float* __restrict__ pw1,
                                                   const float* __restrict__ pb1,
                                                   const float* __restrict__ pw2,
                                                   const float* __restrict__ pb2,
                                                   float* __restrict__ out) {
  __shared__ float r[128], t1[128], z[NCLS];
  int g = blockIdx.x, tid = threadIdx.x;
  r[tid] = reprs[g * 128 + tid];
  __syncthreads();
  float acc = pb1[tid];
  for (int k = 0; k < 128; ++k) acc = fmaf(r[k], pw1[k * 128 + tid], acc);
  t1[tid] = fmaxf(acc, 0.f);
  __syncthreads();
  if (tid < NCLS) {
    float zz = pb2[tid];
    for (int k = 0; k < 128; ++k) zz = fmaf(t1[k], pw2[k * NCLS + tid], zz);
    z[tid] = zz;
  }
  __syncthreads();
  if (tid == 0) {
    float mx = -1e30f;
    for (int c = 0; c < NCLS; ++c) mx = fmaxf(mx, z[c]);
    float s = 0.f;
    for (int c = 0; c < NCLS; ++c) s += expf(z[c] - mx);
    float ls = logf(s) + mx;
    for (int c = 0; c < NCLS; ++c) out[g * NCLS + c] = z[c] - ls;
  }
}

extern "C" void kernel_launch(void* const* d_in, const int* in_sizes, int n_in,
                              void* d_out, int out_size, void* d_ws, size_t ws_size,
                              hipStream_t stream) {
  const float* x     = (const float*)d_in[0];
  const int*   eidx  = (const int*)d_in[1];
  const int*   batch = (const int*)d_in[2];
  const float* pre_w = (const float*)d_in[3];
  const float* pre_b = (const float*)d_in[4];
  const float* w1    = (const float*)d_in[5];
  const float* asrc1 = (const float*)d_in[6];
  const float* adst1 = (const float*)d_in[7];
  const float* b1    = (const float*)d_in[8];
  const float* w2    = (const float*)d_in[9];
  const float* asrc2 = (const float*)d_in[10];
  const float* adst2 = (const float*)d_in[11];
  const float* b2    = (const float*)d_in[12];
  const float* pw1   = (const float*)d_in[13];
  const float* pb1   = (const float*)d_in[14];
  const float* pw2   = (const float*)d_in[15];
  const float* pb2   = (const float*)d_in[16];
  float* out = (float*)d_out;

  const int* esrc = eidx;
  const int* edst = eidx + NEDGES;

  char* wsp = (char*)d_ws;
  size_t off = 0;
  auto alloc = [&](size_t bytes) -> void* {
    void* p = wsp + off;
    off += (bytes + 255) & ~(size_t)255;
    return p;
  };
  float* h        = (float*)alloc((size_t)NNODES * 128 * 4);
  unsigned int* hwb = (unsigned int*)alloc((size_t)NNODES * 64 * 4);
  float* a_s      = (float*)alloc((size_t)NNODES * 2 * 4);
  float* a_d      = (float*)alloc((size_t)NNODES * 2 * 4);
  float* reprs    = (float*)alloc((size_t)NGRAPH * 128 * 4);
  int* gstart     = (int*)alloc((NGRAPH + 1) * 4);
  int* deg        = (int*)alloc((size_t)NNODES * 4);
  int* incl       = (int*)alloc((size_t)NNODES * 4);
  int* row_ptr    = (int*)alloc(((size_t)NNODES + 1) * 4);
  int* cursor     = (int*)alloc((size_t)NNODES * 4);
  int* colv       = (int*)alloc((size_t)NEDGES * 4);
  int* blocksum   = (int*)alloc(512 * 4);

  int nb = (NNODES + 255) / 256;   // 391
  int eb = (NEDGES + 255) / 256;   // 6250
  int wb = NNODES / 4;             // wave-per-node kernels: 256 thr = 4 waves
  int sb = (NNODES + SEG_CHUNK - 1) / SEG_CHUNK;

  // CSR build + graph boundaries
  hipMemsetAsync(deg, 0, (size_t)NNODES * 4, stream);
  hipMemsetAsync(reprs, 0, (size_t)NGRAPH * 128 * 4, stream);
  find_starts<<<1, 256, 0, stream>>>(batch, gstart);
  edge_hist<<<eb, 256, 0, stream>>>(edst, deg);
  scan_block<<<nb, 256, 0, stream>>>(deg, incl, blocksum);
  scan_offsets<<<1, 64, 0, stream>>>(blocksum, nb);
  finalize_csr<<<nb, 256, 0, stream>>>(deg, incl, blocksum, row_ptr, cursor);
  edge_scatter<<<eb, 256, 0, stream>>>(esrc, edst, cursor, colv);

  // pre layer: h0 = relu(x @ pre_w + pre_b)
  gemm128<<<NNODES / 32, 128, 0, stream>>>(x, pre_w, pre_b, h, nullptr, NNODES, FIN, 1);
  seg_sum_fast<<<sb, 128, 0, stream>>>(h, batch, gstart, reprs);

  // GAT layer 1
  gemm128<<<NNODES / 32, 128, 0, stream>>>(h, w1, nullptr, nullptr, hwb, NNODES, HDIM, 0);
  alpha_kernel<<<wb, 256, 0, stream>>>(hwb, asrc1, adst1, a_s, a_d);
  aggregate<<<wb, 256, 0, stream>>>(hwb, a_s, a_d, row_ptr, colv, b1, h);
  seg_sum_fast<<<sb, 128, 0, stream>>>(h, batch, gstart, reprs);

  // GAT layer 2
  gemm128<<<NNODES / 32, 128, 0, stream>>>(h, w2, nullptr, nullptr, hwb, NNODES, HDIM, 0);
  alpha_kernel<<<wb, 256, 0, stream>>>(hwb, asrc2, adst2, a_s, a_d);
  aggregate<<<wb, 256, 0, stream>>>(hwb, a_s, a_d, row_ptr, colv, b2, h);
  seg_sum_fast<<<sb, 128, 0, stream>>>(h, batch, gstart, reprs);

  // head
  head_kernel<<<NGRAPH, 128, 0, stream>>>(reprs, pw1, pb1, pw2, pb2, out);
}

// Round 4
// 854.066 us; speedup vs baseline: 1.7860x; 1.1522x over previous
//
#include <hip/hip_runtime.h>
#include <hip/hip_bf16.h>
#include <math.h>

#define NNODES 100000
#define NEDGES 1600000
#define FIN 256
#define HDIM 128
#define NGRAPH 128
#define NCLS 10
#define NEG 0.2f

typedef short bf8 __attribute__((ext_vector_type(8)));
typedef float f4 __attribute__((ext_vector_type(4)));

__device__ __forceinline__ float lrelu(float x) { return x > 0.f ? x : NEG * x; }

__device__ __forceinline__ unsigned short f2bf(float f) {
  union { float f; unsigned int u; } v; v.f = f;
  unsigned int r = v.u + 0x7fffu + ((v.u >> 16) & 1u);   // round-nearest-even
  return (unsigned short)(r >> 16);
}
__device__ __forceinline__ float bf_lo(unsigned int p) {
  union { unsigned int u; float f; } v; v.u = p << 16; return v.f;
}
__device__ __forceinline__ float bf_hi(unsigned int p) {
  union { unsigned int u; float f; } v; v.u = p & 0xffff0000u; return v.f;
}

// ---------------- one-shot weight convert+transpose: w[K][128] -> wt[128][K] -
__global__ __launch_bounds__(256) void convert_transpose(const float* __restrict__ w,
                                                         unsigned short* __restrict__ wt,
                                                         int K) {
  int i = blockIdx.x * 256 + threadIdx.x;
  if (i >= K * 128) return;
  int k = i >> 7, n = i & 127;
  wt[n * K + k] = f2bf(w[(size_t)k * 128 + n]);
}

// ---------------- MFMA GEMM: [M x 128] = A_f32[M x K] @ Bt_bf16[128 x K] -----
// 256 thr = 4 waves; block tile 128 rows x 128 cols; wave tile 32 x 128.
// LDS: fragment-contiguous blobs (16B per lane) -> linear ds_read_b128.
// Epilogue: C fp32 (+bias,+relu) OR Cp packed bf16 ushort2{head0,head1}.
__global__ __launch_bounds__(256) void gemm_mfma(const float* __restrict__ A,
                                                 const unsigned short* __restrict__ Bt,
                                                 const float* __restrict__ bias,
                                                 float* __restrict__ C,
                                                 unsigned int* __restrict__ Cp,
                                                 int M, int K, int dorelu) {
  __shared__ bf8 As[512];   // 8 KB: blob index mt*64 + lane, mt = m-tile 0..7
  __shared__ bf8 Bs[512];   // 8 KB: blob index tn*64 + lane, tn = n-tile 0..7
  int tid = threadIdx.x;
  int wv = tid >> 6, lane = tid & 63;
  int quad = lane >> 4, m16 = lane & 15;
  int row0 = blockIdx.x * 128;

  f4 acc[2][8];
#pragma unroll
  for (int a = 0; a < 2; ++a)
#pragma unroll
    for (int b = 0; b < 8; ++b) acc[a][b] = (f4){0.f, 0.f, 0.f, 0.f};

  for (int kb = 0; kb < K; kb += 32) {
    __syncthreads();
    // stage A (convert fp32 -> bf16), 2 blobs per thread
#pragma unroll
    for (int bb = 0; bb < 2; ++bb) {
      int b = tid + bb * 256;
      int l = b & 63, mt = b >> 6;
      int row = row0 + mt * 16 + (l & 15);
      if (row > M - 1) row = M - 1;
      const float* src = &A[(size_t)row * K + kb + (l >> 4) * 8];
      float4 x0 = *reinterpret_cast<const float4*>(src);
      float4 x1 = *reinterpret_cast<const float4*>(src + 4);
      bf8 v;
      v[0] = (short)f2bf(x0.x); v[1] = (short)f2bf(x0.y);
      v[2] = (short)f2bf(x0.z); v[3] = (short)f2bf(x0.w);
      v[4] = (short)f2bf(x1.x); v[5] = (short)f2bf(x1.y);
      v[6] = (short)f2bf(x1.z); v[7] = (short)f2bf(x1.w);
      As[b] = v;
    }
    // stage B (already bf16, contiguous 16B per blob)
#pragma unroll
    for (int bb = 0; bb < 2; ++bb) {
      int b = tid + bb * 256;
      int l = b & 63, tn = b >> 6;
      int n = tn * 16 + (l & 15);
      Bs[b] = *reinterpret_cast<const bf8*>(&Bt[(size_t)n * K + kb + (l >> 4) * 8]);
    }
    __syncthreads();
    bf8 af0 = As[(wv * 2 + 0) * 64 + lane];
    bf8 af1 = As[(wv * 2 + 1) * 64 + lane];
#pragma unroll
    for (int tn = 0; tn < 8; ++tn) {
      bf8 bfm = Bs[tn * 64 + lane];
      acc[0][tn] = __builtin_amdgcn_mfma_f32_16x16x32_bf16(af0, bfm, acc[0][tn], 0, 0, 0);
      acc[1][tn] = __builtin_amdgcn_mfma_f32_16x16x32_bf16(af1, bfm, acc[1][tn], 0, 0, 0);
    }
  }

  // epilogue: C row = row0 + wv*32 + mt*16 + quad*4 + r; col = tn*16 + m16
  if (Cp) {
#pragma unroll
    for (int mt = 0; mt < 2; ++mt)
#pragma unroll
      for (int tn = 0; tn < 4; ++tn)
#pragma unroll
        for (int r = 0; r < 4; ++r) {
          int row = row0 + wv * 32 + mt * 16 + quad * 4 + r;
          if (row < M) {
            unsigned int p = (unsigned int)f2bf(acc[mt][tn][r]) |
                             ((unsigned int)f2bf(acc[mt][tn + 4][r]) << 16);
            Cp[(size_t)row * 64 + tn * 16 + m16] = p;
          }
        }
  } else {
#pragma unroll
    for (int mt = 0; mt < 2; ++mt)
#pragma unroll
      for (int tn = 0; tn < 8; ++tn) {
        float bv = bias ? bias[tn * 16 + m16] : 0.f;
#pragma unroll
        for (int r = 0; r < 4; ++r) {
          int row = row0 + wv * 32 + mt * 16 + quad * 4 + r;
          if (row < M) {
            float v = acc[mt][tn][r] + bv;
            if (dorelu) v = fmaxf(v, 0.f);
            C[(size_t)row * 128 + tn * 16 + m16] = v;
          }
        }
      }
  }
}

// ---------------- graph boundaries (batch is sorted) -------------------------
__global__ void find_starts(const int* __restrict__ batch, int* __restrict__ gstart) {
  int g = threadIdx.x;
  if (g > NGRAPH) return;
  if (g == NGRAPH) { gstart[g] = NNODES; return; }
  int lo = 0, hi = NNODES;
  while (lo < hi) { int mid = (lo + hi) >> 1; if (batch[mid] < g) lo = mid + 1; else hi = mid; }
  gstart[g] = lo;
}

// ---------------- CSR build --------------------------------------------------
__global__ __launch_bounds__(256) void edge_hist(const int* __restrict__ dst,
                                                 int* __restrict__ deg) {
  int j = blockIdx.x * 256 + threadIdx.x;
  if (j < NEDGES) atomicAdd(&deg[dst[j]], 1);
}

__global__ __launch_bounds__(256) void scan_block(const int* __restrict__ deg,
                                                  int* __restrict__ incl,
                                                  int* __restrict__ blocksum) {
  __shared__ int s[256];
  int tid = threadIdx.x;
  int i = blockIdx.x * 256 + tid;
  s[tid] = (i < NNODES) ? deg[i] : 0;
  __syncthreads();
  for (int off = 1; off < 256; off <<= 1) {
    int t = (tid >= off) ? s[tid - off] : 0;
    __syncthreads();
    s[tid] += t;
    __syncthreads();
  }
  if (i < NNODES) incl[i] = s[tid];
  if (tid == 255) blocksum[blockIdx.x] = s[255];
}

__global__ void scan_offsets(int* blocksum, int nb) {
  if (threadIdx.x == 0 && blockIdx.x == 0) {
    int run = 0;
    for (int b = 0; b < nb; ++b) { int t = blocksum[b]; blocksum[b] = run; run += t; }
  }
}

__global__ __launch_bounds__(256) void finalize_csr(const int* __restrict__ deg,
                                                    const int* __restrict__ incl,
                                                    const int* __restrict__ blocksum,
                                                    int* __restrict__ row_ptr,
                                                    int* __restrict__ cursor) {
  int i = blockIdx.x * 256 + threadIdx.x;
  if (i >= NNODES) return;
  int tot = incl[i] + blocksum[i >> 8];
  int rp = tot - deg[i];
  row_ptr[i] = rp;
  cursor[i] = rp;
  if (i == NNODES - 1) row_ptr[NNODES] = tot;
}

__global__ __launch_bounds__(256) void edge_scatter(const int* __restrict__ src,
                                                    const int* __restrict__ dst,
                                                    int* __restrict__ cursor,
                                                    int* __restrict__ colv) {
  int j = blockIdx.x * 256 + threadIdx.x;
  if (j < NEDGES) {
    int d = dst[j];
    int pos = atomicAdd(&cursor[d], 1);
    colv[pos] = src[j];
  }
}

// ---------------- per-node attention logits (packed bf16 input) --------------
__global__ __launch_bounds__(256) void alpha_kernel(const unsigned int* __restrict__ hwb,
                                                    const float* __restrict__ aw_src,
                                                    const float* __restrict__ aw_dst,
                                                    float* __restrict__ a_s,
                                                    float* __restrict__ a_d) {
  int wid = (blockIdx.x * 256 + threadIdx.x) >> 6;
  int lane = threadIdx.x & 63;
  if (wid >= NNODES) return;
  unsigned int p = hwb[(size_t)wid * 64 + lane];
  float v0 = bf_lo(p), v1 = bf_hi(p);
  float s0 = v0 * aw_src[lane], s1 = v1 * aw_src[64 + lane];
  float d0 = v0 * aw_dst[lane], d1 = v1 * aw_dst[64 + lane];
  for (int o = 32; o; o >>= 1) {
    s0 += __shfl_xor(s0, o); s1 += __shfl_xor(s1, o);
    d0 += __shfl_xor(d0, o); d1 += __shfl_xor(d1, o);
  }
  if (lane == 0) {
    a_s[2 * wid] = s0; a_s[2 * wid + 1] = s1;
    a_d[2 * wid] = d0; a_d[2 * wid + 1] = d1;
  }
}

// ---------------- softmax aggregation: one wave per dst node -----------------
__global__ __launch_bounds__(256) void aggregate(const unsigned int* __restrict__ hwb,
                                                 const float* __restrict__ a_s,
                                                 const float* __restrict__ a_d,
                                                 const int* __restrict__ row_ptr,
                                                 const int* __restrict__ colv,
                                                 const float* __restrict__ bias,
                                                 float* __restrict__ out) {
  int i = (blockIdx.x * 256 + threadIdx.x) >> 6;
  int lane = threadIdx.x & 63;
  if (i >= NNODES) return;
  float ad0 = a_d[2 * i], ad1 = a_d[2 * i + 1];
  float es0 = lrelu(a_s[2 * i] + ad0), es1 = lrelu(a_s[2 * i + 1] + ad1);  // self edge
  int start = row_ptr[i], end = row_ptr[i + 1];
  int deg = end - start;

  // lane-parallel logits for first <=64 edges
  int sl = 0; float e0l = -1e30f, e1l = -1e30f;
  if (lane < deg) {
    sl = colv[start + lane];
    float2 av = *reinterpret_cast<const float2*>(&a_s[2 * sl]);
    e0l = lrelu(av.x + ad0); e1l = lrelu(av.y + ad1);
  }
  // max (self + all edges)
  float m0 = fmaxf(es0, e0l), m1 = fmaxf(es1, e1l);
  for (int j = start + 64 + lane; j < end; j += 64) {
    int s = colv[j];
    float2 av = *reinterpret_cast<const float2*>(&a_s[2 * s]);
    m0 = fmaxf(m0, lrelu(av.x + ad0));
    m1 = fmaxf(m1, lrelu(av.y + ad1));
  }
  for (int o = 32; o; o >>= 1) {
    m0 = fmaxf(m0, __shfl_xor(m0, o));
    m1 = fmaxf(m1, __shfl_xor(m1, o));
  }
  // lane-parallel weights + denominator
  float w0l = lane < deg ? __expf(e0l - m0) : 0.f;
  float w1l = lane < deg ? __expf(e1l - m1) : 0.f;
  float d0 = w0l, d1 = w1l;
  for (int o = 32; o; o >>= 1) { d0 += __shfl_xor(d0, o); d1 += __shfl_xor(d1, o); }
  float ws0 = __expf(es0 - m0), ws1 = __expf(es1 - m1);
  float den0 = d0 + ws0, den1 = d1 + ws1;

  // accumulate: self, then broadcast loop (shfl weights, gather packed bf16)
  unsigned int ps = hwb[(size_t)i * 64 + lane];
  float acc0 = ws0 * bf_lo(ps), acc1 = ws1 * bf_hi(ps);
  int dmin = deg < 64 ? deg : 64;
  for (int t = 0; t < dmin; ++t) {
    int s = __shfl(sl, t);
    float w0 = __shfl(w0l, t), w1 = __shfl(w1l, t);
    unsigned int q = hwb[(size_t)s * 64 + lane];
    acc0 = fmaf(w0, bf_lo(q), acc0);
    acc1 = fmaf(w1, bf_hi(q), acc1);
  }
  for (int j = start + 64; j < end; ++j) {   // rare overflow path (deg > 64)
    int s = colv[j];
    float2 av = *reinterpret_cast<const float2*>(&a_s[2 * s]);
    float w0 = __expf(lrelu(av.x + ad0) - m0);
    float w1 = __expf(lrelu(av.y + ad1) - m1);
    den0 += w0; den1 += w1;
    unsigned int q = hwb[(size_t)s * 64 + lane];
    acc0 = fmaf(w0, bf_lo(q), acc0);
    acc1 = fmaf(w1, bf_hi(q), acc1);
  }
  out[(size_t)i * 128 + lane]      = fmaxf(acc0 / den0 + bias[lane], 0.f);
  out[(size_t)i * 128 + 64 + lane] = fmaxf(acc1 / den1 + bias[64 + lane], 0.f);
}

// ---------------- per-graph pooling, node-parallel ---------------------------
#define SEG_CHUNK 128
__global__ __launch_bounds__(128) void seg_sum_fast(const float* __restrict__ h,
                                                    const int* __restrict__ batch,
                                                    const int* __restrict__ gstart,
                                                    float* __restrict__ reprs) {
  int n0 = blockIdx.x * SEG_CHUNK;
  if (n0 >= NNODES) return;
  int nend = n0 + SEG_CHUNK; if (nend > NNODES) nend = NNODES;
  int tid = threadIdx.x;
  int r = n0;
  while (r < nend) {
    int g = batch[r];
    int segend = gstart[g + 1]; if (segend > nend) segend = nend;
    float a0 = 0.f, a1 = 0.f, a2 = 0.f, a3 = 0.f;
    for (; r + 3 < segend; r += 4) {
      a0 += h[(size_t)r * 128 + tid];
      a1 += h[(size_t)(r + 1) * 128 + tid];
      a2 += h[(size_t)(r + 2) * 128 + tid];
      a3 += h[(size_t)(r + 3) * 128 + tid];
    }
    for (; r < segend; ++r) a0 += h[(size_t)r * 128 + tid];
    atomicAdd(&reprs[g * 128 + tid], (a0 + a1) + (a2 + a3));
  }
}

// ---------------- head MLP + log_softmax -------------------------------------
__global__ __launch_bounds__(128) void head_kernel(const float* __restrict__ reprs,
                                                   const float* __restrict__ pw1,
                                                   const float* __restrict__ pb1,
                                                   const float* __restrict__ pw2,
                                                   const float* __restrict__ pb2,
                                                   float* __restrict__ out) {
  __shared__ float r[128], t1[128], z[NCLS];
  int g = blockIdx.x, tid = threadIdx.x;
  r[tid] = reprs[g * 128 + tid];
  __syncthreads();
  float acc = pb1[tid];
  for (int k = 0; k < 128; ++k) acc = fmaf(r[k], pw1[k * 128 + tid], acc);
  t1[tid] = fmaxf(acc, 0.f);
  __syncthreads();
  if (tid < NCLS) {
    float zz = pb2[tid];
    for (int k = 0; k < 128; ++k) zz = fmaf(t1[k], pw2[k * NCLS + tid], zz);
    z[tid] = zz;
  }
  __syncthreads();
  if (tid == 0) {
    float mx = -1e30f;
    for (int c = 0; c < NCLS; ++c) mx = fmaxf(mx, z[c]);
    float s = 0.f;
    for (int c = 0; c < NCLS; ++c) s += expf(z[c] - mx);
    float ls = logf(s) + mx;
    for (int c = 0; c < NCLS; ++c) out[g * NCLS + c] = z[c] - ls;
  }
}

extern "C" void kernel_launch(void* const* d_in, const int* in_sizes, int n_in,
                              void* d_out, int out_size, void* d_ws, size_t ws_size,
                              hipStream_t stream) {
  const float* x     = (const float*)d_in[0];
  const int*   eidx  = (const int*)d_in[1];
  const int*   batch = (const int*)d_in[2];
  const float* pre_w = (const float*)d_in[3];
  const float* pre_b = (const float*)d_in[4];
  const float* w1    = (const float*)d_in[5];
  const float* asrc1 = (const float*)d_in[6];
  const float* adst1 = (const float*)d_in[7];
  const float* b1    = (const float*)d_in[8];
  const float* w2    = (const float*)d_in[9];
  const float* asrc2 = (const float*)d_in[10];
  const float* adst2 = (const float*)d_in[11];
  const float* b2    = (const float*)d_in[12];
  const float* pw1   = (const float*)d_in[13];
  const float* pb1   = (const float*)d_in[14];
  const float* pw2   = (const float*)d_in[15];
  const float* pb2   = (const float*)d_in[16];
  float* out = (float*)d_out;

  const int* esrc = eidx;
  const int* edst = eidx + NEDGES;

  char* wsp = (char*)d_ws;
  size_t off = 0;
  auto alloc = [&](size_t bytes) -> void* {
    void* p = wsp + off;
    off += (bytes + 255) & ~(size_t)255;
    return p;
  };
  float* h          = (float*)alloc((size_t)NNODES * 128 * 4);
  unsigned int* hwb = (unsigned int*)alloc((size_t)NNODES * 64 * 4);
  float* a_s        = (float*)alloc((size_t)NNODES * 2 * 4);
  float* a_d        = (float*)alloc((size_t)NNODES * 2 * 4);
  float* reprs      = (float*)alloc((size_t)NGRAPH * 128 * 4);
  int* gstart       = (int*)alloc((NGRAPH + 1) * 4);
  int* deg          = (int*)alloc((size_t)NNODES * 4);
  int* incl         = (int*)alloc((size_t)NNODES * 4);
  int* row_ptr      = (int*)alloc(((size_t)NNODES + 1) * 4);
  int* cursor       = (int*)alloc((size_t)NNODES * 4);
  int* colv         = (int*)alloc((size_t)NEDGES * 4);
  int* blocksum     = (int*)alloc(512 * 4);
  unsigned short* wt_pre = (unsigned short*)alloc((size_t)128 * FIN * 2);
  unsigned short* wt1    = (unsigned short*)alloc((size_t)128 * HDIM * 2);
  unsigned short* wt2    = (unsigned short*)alloc((size_t)128 * HDIM * 2);

  int nb = (NNODES + 255) / 256;   // 391
  int eb = (NEDGES + 255) / 256;   // 6250
  int wb = NNODES / 4;             // wave-per-node kernels: 256 thr = 4 waves
  int sb = (NNODES + SEG_CHUNK - 1) / SEG_CHUNK;
  int gb = (NNODES + 127) / 128;   // 782 GEMM blocks

  // one-shot weight conversion (bf16, transposed)
  convert_transpose<<<(FIN * 128 + 255) / 256, 256, 0, stream>>>(pre_w, wt_pre, FIN);
  convert_transpose<<<(HDIM * 128 + 255) / 256, 256, 0, stream>>>(w1, wt1, HDIM);
  convert_transpose<<<(HDIM * 128 + 255) / 256, 256, 0, stream>>>(w2, wt2, HDIM);

  // CSR build + graph boundaries
  hipMemsetAsync(deg, 0, (size_t)NNODES * 4, stream);
  hipMemsetAsync(reprs, 0, (size_t)NGRAPH * 128 * 4, stream);
  find_starts<<<1, 256, 0, stream>>>(batch, gstart);
  edge_hist<<<eb, 256, 0, stream>>>(edst, deg);
  scan_block<<<nb, 256, 0, stream>>>(deg, incl, blocksum);
  scan_offsets<<<1, 64, 0, stream>>>(blocksum, nb);
  finalize_csr<<<nb, 256, 0, stream>>>(deg, incl, blocksum, row_ptr, cursor);
  edge_scatter<<<eb, 256, 0, stream>>>(esrc, edst, cursor, colv);

  // pre layer: h0 = relu(x @ pre_w + pre_b)
  gemm_mfma<<<gb, 256, 0, stream>>>(x, wt_pre, pre_b, h, nullptr, NNODES, FIN, 1);
  seg_sum_fast<<<sb, 128, 0, stream>>>(h, batch, gstart, reprs);

  // GAT layer 1
  gemm_mfma<<<gb, 256, 0, stream>>>(h, wt1, nullptr, nullptr, hwb, NNODES, HDIM, 0);
  alpha_kernel<<<wb, 256, 0, stream>>>(hwb, asrc1, adst1, a_s, a_d);
  aggregate<<<wb, 256, 0, stream>>>(hwb, a_s, a_d, row_ptr, colv, b1, h);
  seg_sum_fast<<<sb, 128, 0, stream>>>(h, batch, gstart, reprs);

  // GAT layer 2
  gemm_mfma<<<gb, 256, 0, stream>>>(h, wt2, nullptr, nullptr, hwb, NNODES, HDIM, 0);
  alpha_kernel<<<wb, 256, 0, stream>>>(hwb, asrc2, adst2, a_s, a_d);
  aggregate<<<wb, 256, 0, stream>>>(hwb, a_s, a_d, row_ptr, colv, b2, h);
  seg_sum_fast<<<sb, 128, 0, stream>>>(h, batch, gstart, reprs);

  // head
  head_kernel<<<NGRAPH, 128, 0, stream>>>(reprs, pw1, pb1, pw2, pb2, out);
}

// Round 5
// 716.203 us; speedup vs baseline: 2.1298x; 1.1925x over previous
//
#include <hip/hip_runtime.h>
#include <hip/hip_bf16.h>
#include <math.h>

#define NNODES 100000
#define NEDGES 1600000
#define FIN 256
#define HDIM 128
#define NGRAPH 128
#define NCLS 10
#define NEG 0.2f

#define NBUCK 98            // buckets of 1024 dst nodes (100000 >> 10 -> 0..97)
#define EPB 4096            // edges per bin_place block
#define EBLK ((NEDGES + EPB - 1) / EPB)   // 391

typedef short bf8 __attribute__((ext_vector_type(8)));
typedef float f4 __attribute__((ext_vector_type(4)));

__device__ __forceinline__ float lrelu(float x) { return x > 0.f ? x : NEG * x; }

__device__ __forceinline__ unsigned short f2bf(float f) {
  union { float f; unsigned int u; } v; v.f = f;
  unsigned int r = v.u + 0x7fffu + ((v.u >> 16) & 1u);   // round-nearest-even
  return (unsigned short)(r >> 16);
}
__device__ __forceinline__ float bf_lo(unsigned int p) {
  union { unsigned int u; float f; } v; v.u = p << 16; return v.f;
}
__device__ __forceinline__ float bf_hi(unsigned int p) {
  union { unsigned int u; float f; } v; v.u = p & 0xffff0000u; return v.f;
}

// ---------------- one-shot weight convert+transpose: w[K][128] -> wt[128][K] -
__global__ __launch_bounds__(256) void convert_transpose(const float* __restrict__ w,
                                                         unsigned short* __restrict__ wt,
                                                         int K) {
  int i = blockIdx.x * 256 + threadIdx.x;
  if (i >= K * 128) return;
  int k = i >> 7, n = i & 127;
  wt[n * K + k] = f2bf(w[(size_t)k * 128 + n]);
}

// ---------------- MFMA GEMM (unchanged from R3) ------------------------------
__global__ __launch_bounds__(256) void gemm_mfma(const float* __restrict__ A,
                                                 const unsigned short* __restrict__ Bt,
                                                 const float* __restrict__ bias,
                                                 float* __restrict__ C,
                                                 unsigned int* __restrict__ Cp,
                                                 int M, int K, int dorelu) {
  __shared__ bf8 As[512];
  __shared__ bf8 Bs[512];
  int tid = threadIdx.x;
  int wv = tid >> 6, lane = tid & 63;
  int quad = lane >> 4, m16 = lane & 15;
  int row0 = blockIdx.x * 128;

  f4 acc[2][8];
#pragma unroll
  for (int a = 0; a < 2; ++a)
#pragma unroll
    for (int b = 0; b < 8; ++b) acc[a][b] = (f4){0.f, 0.f, 0.f, 0.f};

  for (int kb = 0; kb < K; kb += 32) {
    __syncthreads();
#pragma unroll
    for (int bb = 0; bb < 2; ++bb) {
      int b = tid + bb * 256;
      int l = b & 63, mt = b >> 6;
      int row = row0 + mt * 16 + (l & 15);
      if (row > M - 1) row = M - 1;
      const float* src = &A[(size_t)row * K + kb + (l >> 4) * 8];
      float4 x0 = *reinterpret_cast<const float4*>(src);
      float4 x1 = *reinterpret_cast<const float4*>(src + 4);
      bf8 v;
      v[0] = (short)f2bf(x0.x); v[1] = (short)f2bf(x0.y);
      v[2] = (short)f2bf(x0.z); v[3] = (short)f2bf(x0.w);
      v[4] = (short)f2bf(x1.x); v[5] = (short)f2bf(x1.y);
      v[6] = (short)f2bf(x1.z); v[7] = (short)f2bf(x1.w);
      As[b] = v;
    }
#pragma unroll
    for (int bb = 0; bb < 2; ++bb) {
      int b = tid + bb * 256;
      int l = b & 63, tn = b >> 6;
      int n = tn * 16 + (l & 15);
      Bs[b] = *reinterpret_cast<const bf8*>(&Bt[(size_t)n * K + kb + (l >> 4) * 8]);
    }
    __syncthreads();
    bf8 af0 = As[(wv * 2 + 0) * 64 + lane];
    bf8 af1 = As[(wv * 2 + 1) * 64 + lane];
#pragma unroll
    for (int tn = 0; tn < 8; ++tn) {
      bf8 bfm = Bs[tn * 64 + lane];
      acc[0][tn] = __builtin_amdgcn_mfma_f32_16x16x32_bf16(af0, bfm, acc[0][tn], 0, 0, 0);
      acc[1][tn] = __builtin_amdgcn_mfma_f32_16x16x32_bf16(af1, bfm, acc[1][tn], 0, 0, 0);
    }
  }

  if (Cp) {
#pragma unroll
    for (int mt = 0; mt < 2; ++mt)
#pragma unroll
      for (int tn = 0; tn < 4; ++tn)
#pragma unroll
        for (int r = 0; r < 4; ++r) {
          int row = row0 + wv * 32 + mt * 16 + quad * 4 + r;
          if (row < M) {
            unsigned int p = (unsigned int)f2bf(acc[mt][tn][r]) |
                             ((unsigned int)f2bf(acc[mt][tn + 4][r]) << 16);
            Cp[(size_t)row * 64 + tn * 16 + m16] = p;
          }
        }
  } else {
#pragma unroll
    for (int mt = 0; mt < 2; ++mt)
#pragma unroll
      for (int tn = 0; tn < 8; ++tn) {
        float bv = bias ? bias[tn * 16 + m16] : 0.f;
#pragma unroll
        for (int r = 0; r < 4; ++r) {
          int row = row0 + wv * 32 + mt * 16 + quad * 4 + r;
          if (row < M) {
            float v = acc[mt][tn][r] + bv;
            if (dorelu) v = fmaxf(v, 0.f);
            C[(size_t)row * 128 + tn * 16 + m16] = v;
          }
        }
      }
  }
}

// ---------------- graph boundaries (batch is sorted) -------------------------
__global__ void find_starts(const int* __restrict__ batch, int* __restrict__ gstart) {
  int g = threadIdx.x;
  if (g > NGRAPH) return;
  if (g == NGRAPH) { gstart[g] = NNODES; return; }
  int lo = 0, hi = NNODES;
  while (lo < hi) { int mid = (lo + hi) >> 1; if (batch[mid] < g) lo = mid + 1; else hi = mid; }
  gstart[g] = lo;
}

// ======== CSR build, bucketed two-phase (no random global atomics) ==========
// Phase A0: per-block bucket histogram (LDS atomics, coalesced global write)
__global__ __launch_bounds__(256) void bin_count(const int* __restrict__ edst,
                                                 int* __restrict__ blockHist) {
  __shared__ int hist[NBUCK];
  int t = threadIdx.x, blk = blockIdx.x;
  if (t < NBUCK) hist[t] = 0;
  __syncthreads();
  int e0 = blk * EPB;
#pragma unroll
  for (int it = 0; it < EPB / 256; ++it) {
    int e = e0 + it * 256 + t;
    if (e < NEDGES) atomicAdd(&hist[((unsigned)edst[e]) >> 10], 1);
  }
  __syncthreads();
  if (t < NBUCK) blockHist[blk * NBUCK + t] = hist[t];
}

// Phase A0.5a: per-bucket scan over blocks -> exclusive base per (bucket,block)
__global__ __launch_bounds__(512) void colscan(const int* __restrict__ blockHist,
                                               int* __restrict__ blockBaseCol,
                                               int* __restrict__ bucket_total) {
  __shared__ int s[512];
  int b = blockIdx.x, t = threadIdx.x;
  int v = (t < EBLK) ? blockHist[t * NBUCK + b] : 0;
  s[t] = v;
  __syncthreads();
  for (int off = 1; off < 512; off <<= 1) {
    int u = (t >= off) ? s[t - off] : 0;
    __syncthreads();
    s[t] += u;
    __syncthreads();
  }
  if (t < EBLK) blockBaseCol[b * EBLK + t] = s[t] - v;
  if (t == 511) bucket_total[b] = s[511];
}

// Phase A0.5b: scan bucket totals -> bucket_ptr[0..NBUCK]
__global__ __launch_bounds__(128) void bscan(const int* __restrict__ bucket_total,
                                             int* __restrict__ bucket_ptr) {
  __shared__ int s[128];
  int t = threadIdx.x;
  int v = (t < NBUCK) ? bucket_total[t] : 0;
  s[t] = v;
  __syncthreads();
  for (int off = 1; off < 128; off <<= 1) {
    int u = (t >= off) ? s[t - off] : 0;
    __syncthreads();
    s[t] += u;
    __syncthreads();
  }
  if (t < NBUCK) bucket_ptr[t] = s[t] - v;
  if (t == 127) bucket_ptr[NBUCK] = s[127];
}

// Phase A1: block-level counting sort by bucket, grouped coalesced write-out
__global__ __launch_bounds__(512) void bin_place(const int* __restrict__ esrc,
                                                 const int* __restrict__ edst,
                                                 const int* __restrict__ blockBaseCol,
                                                 const int* __restrict__ bucket_ptr,
                                                 uint2* __restrict__ stagingG) {
  __shared__ int hist[NBUCK + 1], lbase[NBUCK + 1], lcur[NBUCK + 1], cbase[NBUCK];
  __shared__ int tmp[128];
  __shared__ uint2 st[EPB];
  int t = threadIdx.x, blk = blockIdx.x;
  if (t < NBUCK + 1) hist[t] = 0;
  __syncthreads();
  int e0 = blk * EPB;
#pragma unroll
  for (int it = 0; it < EPB / 512; ++it) {
    int e = e0 + it * 512 + t;
    int b = NBUCK;
    if (e < NEDGES) b = ((unsigned)edst[e]) >> 10;
    atomicAdd(&hist[b], 1);
  }
  __syncthreads();
  // exclusive scan of hist[0..NBUCK] (99 values) via 128-wide Hillis-Steele
  if (t < 128) tmp[t] = (t < NBUCK + 1) ? hist[t] : 0;
  __syncthreads();
  for (int off = 1; off < 128; off <<= 1) {
    int u = 0;
    if (t < 128 && t >= off) u = tmp[t - off];
    __syncthreads();
    if (t < 128) tmp[t] += u;
    __syncthreads();
  }
  if (t < NBUCK + 1) { int ex = tmp[t] - hist[t]; lbase[t] = ex; lcur[t] = ex; }
  if (t < NBUCK) cbase[t] = bucket_ptr[t] + blockBaseCol[t * EBLK + blk];
  __syncthreads();
  // place edges into LDS staging grouped by bucket
#pragma unroll
  for (int it = 0; it < EPB / 512; ++it) {
    int e = e0 + it * 512 + t;
    unsigned s = 0, d = 0xFFFFFFFFu;
    if (e < NEDGES) { s = (unsigned)esrc[e]; d = (unsigned)edst[e]; }
    int b = (d == 0xFFFFFFFFu) ? NBUCK : (int)(d >> 10);
    int slot = atomicAdd(&lcur[b], 1);
    st[slot] = make_uint2(s, d);
  }
  __syncthreads();
  // grouped write-out: consecutive slots of a bucket -> consecutive global pos
  for (int i = t; i < EPB; i += 512) {
    uint2 ed = st[i];
    if (ed.y == 0xFFFFFFFFu) continue;
    int b = (int)(ed.y >> 10);
    stagingG[cbase[b] + (i - lbase[b])] = ed;
  }
}

// Phase B1: per-bucket degree histogram (LDS atomics, coalesced deg write)
__global__ __launch_bounds__(1024) void bucket_deg(const uint2* __restrict__ stagingG,
                                                   const int* __restrict__ bucket_ptr,
                                                   int* __restrict__ deg) {
  __shared__ int dl[1024];
  int b = blockIdx.x, t = threadIdx.x;
  dl[t] = 0;
  __syncthreads();
  int s0 = bucket_ptr[b], s1 = bucket_ptr[b + 1];
  for (int j = s0 + t; j < s1; j += 1024)
    atomicAdd(&dl[stagingG[j].y & 1023], 1);
  __syncthreads();
  int n = (b << 10) + t;
  if (n < NNODES) deg[n] = dl[t];
}

// ---------------- global scans over deg -> row_ptr ---------------------------
__global__ __launch_bounds__(256) void scan_block(const int* __restrict__ deg,
                                                  int* __restrict__ incl,
                                                  int* __restrict__ blocksum) {
  __shared__ int s[256];
  int tid = threadIdx.x;
  int i = blockIdx.x * 256 + tid;
  s[tid] = (i < NNODES) ? deg[i] : 0;
  __syncthreads();
  for (int off = 1; off < 256; off <<= 1) {
    int t = (tid >= off) ? s[tid - off] : 0;
    __syncthreads();
    s[tid] += t;
    __syncthreads();
  }
  if (i < NNODES) incl[i] = s[tid];
  if (tid == 255) blocksum[blockIdx.x] = s[255];
}

__global__ void scan_offsets(int* blocksum, int nb) {
  if (threadIdx.x == 0 && blockIdx.x == 0) {
    int run = 0;
    for (int b = 0; b < nb; ++b) { int t = blocksum[b]; blocksum[b] = run; run += t; }
  }
}

__global__ __launch_bounds__(256) void finalize_csr(const int* __restrict__ deg,
                                                    const int* __restrict__ incl,
                                                    const int* __restrict__ blocksum,
                                                    int* __restrict__ row_ptr) {
  int i = blockIdx.x * 256 + threadIdx.x;
  if (i >= NNODES) return;
  int tot = incl[i] + blocksum[i >> 8];
  row_ptr[i] = tot - deg[i];
  if (i == NNODES - 1) row_ptr[NNODES] = tot;
}

// Phase B2: exact placement, scatter confined to L2-resident 70KB window
__global__ __launch_bounds__(1024) void bucket_csr(const uint2* __restrict__ stagingG,
                                                   const int* __restrict__ bucket_ptr,
                                                   const int* __restrict__ row_ptr,
                                                   int* __restrict__ colv) {
  __shared__ int cur[1024];
  int b = blockIdx.x, t = threadIdx.x;
  int n = (b << 10) + t;
  cur[t] = (n < NNODES) ? row_ptr[n] : 0;
  __syncthreads();
  int s0 = bucket_ptr[b], s1 = bucket_ptr[b + 1];
  for (int j = s0 + t; j < s1; j += 1024) {
    uint2 e = stagingG[j];
    int pos = atomicAdd(&cur[e.y & 1023], 1);
    colv[pos] = (int)e.x;
  }
}

// ---------------- per-node attention logits (packed bf16 input) --------------
__global__ __launch_bounds__(256) void alpha_kernel(const unsigned int* __restrict__ hwb,
                                                    const float* __restrict__ aw_src,
                                                    const float* __restrict__ aw_dst,
                                                    float* __restrict__ a_s,
                                                    float* __restrict__ a_d) {
  int wid = (blockIdx.x * 256 + threadIdx.x) >> 6;
  int lane = threadIdx.x & 63;
  if (wid >= NNODES) return;
  unsigned int p = hwb[(size_t)wid * 64 + lane];
  float v0 = bf_lo(p), v1 = bf_hi(p);
  float s0 = v0 * aw_src[lane], s1 = v1 * aw_src[64 + lane];
  float d0 = v0 * aw_dst[lane], d1 = v1 * aw_dst[64 + lane];
  for (int o = 32; o; o >>= 1) {
    s0 += __shfl_xor(s0, o); s1 += __shfl_xor(s1, o);
    d0 += __shfl_xor(d0, o); d1 += __shfl_xor(d1, o);
  }
  if (lane == 0) {
    a_s[2 * wid] = s0; a_s[2 * wid + 1] = s1;
    a_d[2 * wid] = d0; a_d[2 * wid + 1] = d1;
  }
}

// ---------------- softmax aggregation: one wave per dst node -----------------
__global__ __launch_bounds__(256) void aggregate(const unsigned int* __restrict__ hwb,
                                                 const float* __restrict__ a_s,
                                                 const float* __restrict__ a_d,
                                                 const int* __restrict__ row_ptr,
                                                 const int* __restrict__ colv,
                                                 const float* __restrict__ bias,
                                                 float* __restrict__ out) {
  int i = (blockIdx.x * 256 + threadIdx.x) >> 6;
  int lane = threadIdx.x & 63;
  if (i >= NNODES) return;
  float ad0 = a_d[2 * i], ad1 = a_d[2 * i + 1];
  float es0 = lrelu(a_s[2 * i] + ad0), es1 = lrelu(a_s[2 * i + 1] + ad1);  // self edge
  int start = row_ptr[i], end = row_ptr[i + 1];
  int deg = end - start;

  int sl = 0; float e0l = -1e30f, e1l = -1e30f;
  if (lane < deg) {
    sl = colv[start + lane];
    float2 av = *reinterpret_cast<const float2*>(&a_s[2 * sl]);
    e0l = lrelu(av.x + ad0); e1l = lrelu(av.y + ad1);
  }
  float m0 = fmaxf(es0, e0l), m1 = fmaxf(es1, e1l);
  for (int j = start + 64 + lane; j < end; j += 64) {
    int s = colv[j];
    float2 av = *reinterpret_cast<const float2*>(&a_s[2 * s]);
    m0 = fmaxf(m0, lrelu(av.x + ad0));
    m1 = fmaxf(m1, lrelu(av.y + ad1));
  }
  for (int o = 32; o; o >>= 1) {
    m0 = fmaxf(m0, __shfl_xor(m0, o));
    m1 = fmaxf(m1, __shfl_xor(m1, o));
  }
  float w0l = lane < deg ? __expf(e0l - m0) : 0.f;
  float w1l = lane < deg ? __expf(e1l - m1) : 0.f;
  float d0 = w0l, d1 = w1l;
  for (int o = 32; o; o >>= 1) { d0 += __shfl_xor(d0, o); d1 += __shfl_xor(d1, o); }
  float ws0 = __expf(es0 - m0), ws1 = __expf(es1 - m1);
  float den0 = d0 + ws0, den1 = d1 + ws1;

  unsigned int ps = hwb[(size_t)i * 64 + lane];
  float acc0 = ws0 * bf_lo(ps), acc1 = ws1 * bf_hi(ps);
  int dmin = deg < 64 ? deg : 64;
  for (int t = 0; t < dmin; ++t) {
    int s = __shfl(sl, t);
    float w0 = __shfl(w0l, t), w1 = __shfl(w1l, t);
    unsigned int q = hwb[(size_t)s * 64 + lane];
    acc0 = fmaf(w0, bf_lo(q), acc0);
    acc1 = fmaf(w1, bf_hi(q), acc1);
  }
  for (int j = start + 64; j < end; ++j) {
    int s = colv[j];
    float2 av = *reinterpret_cast<const float2*>(&a_s[2 * s]);
    float w0 = __expf(lrelu(av.x + ad0) - m0);
    float w1 = __expf(lrelu(av.y + ad1) - m1);
    den0 += w0; den1 += w1;
    unsigned int q = hwb[(size_t)s * 64 + lane];
    acc0 = fmaf(w0, bf_lo(q), acc0);
    acc1 = fmaf(w1, bf_hi(q), acc1);
  }
  out[(size_t)i * 128 + lane]      = fmaxf(acc0 / den0 + bias[lane], 0.f);
  out[(size_t)i * 128 + 64 + lane] = fmaxf(acc1 / den1 + bias[64 + lane], 0.f);
}

// ---------------- per-graph pooling, node-parallel ---------------------------
#define SEG_CHUNK 128
__global__ __launch_bounds__(128) void seg_sum_fast(const float* __restrict__ h,
                                                    const int* __restrict__ batch,
                                                    const int* __restrict__ gstart,
                                                    float* __restrict__ reprs) {
  int n0 = blockIdx.x * SEG_CHUNK;
  if (n0 >= NNODES) return;
  int nend = n0 + SEG_CHUNK; if (nend > NNODES) nend = NNODES;
  int tid = threadIdx.x;
  int r = n0;
  while (r < nend) {
    int g = batch[r];
    int segend = gstart[g + 1]; if (segend > nend) segend = nend;
    float a0 = 0.f, a1 = 0.f, a2 = 0.f, a3 = 0.f;
    for (; r + 3 < segend; r += 4) {
      a0 += h[(size_t)r * 128 + tid];
      a1 += h[(size_t)(r + 1) * 128 + tid];
      a2 += h[(size_t)(r + 2) * 128 + tid];
      a3 += h[(size_t)(r + 3) * 128 + tid];
    }
    for (; r < segend; ++r) a0 += h[(size_t)r * 128 + tid];
    atomicAdd(&reprs[g * 128 + tid], (a0 + a1) + (a2 + a3));
  }
}

// ---------------- head MLP + log_softmax -------------------------------------
__global__ __launch_bounds__(128) void head_kernel(const float* __restrict__ reprs,
                                                   const float* __restrict__ pw1,
                                                   const float* __restrict__ pb1,
                                                   const float* __restrict__ pw2,
                                                   const float* __restrict__ pb2,
                                                   float* __restrict__ out) {
  __shared__ float r[128], t1[128], z[NCLS];
  int g = blockIdx.x, tid = threadIdx.x;
  r[tid] = reprs[g * 128 + tid];
  __syncthreads();
  float acc = pb1[tid];
  for (int k = 0; k < 128; ++k) acc = fmaf(r[k], pw1[k * 128 + tid], acc);
  t1[tid] = fmaxf(acc, 0.f);
  __syncthreads();
  if (tid < NCLS) {
    float zz = pb2[tid];
    for (int k = 0; k < 128; ++k) zz = fmaf(t1[k], pw2[k * NCLS + tid], zz);
    z[tid] = zz;
  }
  __syncthreads();
  if (tid == 0) {
    float mx = -1e30f;
    for (int c = 0; c < NCLS; ++c) mx = fmaxf(mx, z[c]);
    float s = 0.f;
    for (int c = 0; c < NCLS; ++c) s += expf(z[c] - mx);
    float ls = logf(s) + mx;
    for (int c = 0; c < NCLS; ++c) out[g * NCLS + c] = z[c] - ls;
  }
}

extern "C" void kernel_launch(void* const* d_in, const int* in_sizes, int n_in,
                              void* d_out, int out_size, void* d_ws, size_t ws_size,
                              hipStream_t stream) {
  const float* x     = (const float*)d_in[0];
  const int*   eidx  = (const int*)d_in[1];
  const int*   batch = (const int*)d_in[2];
  const float* pre_w = (const float*)d_in[3];
  const float* pre_b = (const float*)d_in[4];
  const float* w1    = (const float*)d_in[5];
  const float* asrc1 = (const float*)d_in[6];
  const float* adst1 = (const float*)d_in[7];
  const float* b1    = (const float*)d_in[8];
  const float* w2    = (const float*)d_in[9];
  const float* asrc2 = (const float*)d_in[10];
  const float* adst2 = (const float*)d_in[11];
  const float* b2    = (const float*)d_in[12];
  const float* pw1   = (const float*)d_in[13];
  const float* pb1   = (const float*)d_in[14];
  const float* pw2   = (const float*)d_in[15];
  const float* pb2   = (const float*)d_in[16];
  float* out = (float*)d_out;

  const int* esrc = eidx;
  const int* edst = eidx + NEDGES;

  char* wsp = (char*)d_ws;
  size_t off = 0;
  auto alloc = [&](size_t bytes) -> void* {
    void* p = wsp + off;
    off += (bytes + 255) & ~(size_t)255;
    return p;
  };
  float* h          = (float*)alloc((size_t)NNODES * 128 * 4);
  unsigned int* hwb = (unsigned int*)alloc((size_t)NNODES * 64 * 4);
  float* a_s        = (float*)alloc((size_t)NNODES * 2 * 4);
  float* a_d        = (float*)alloc((size_t)NNODES * 2 * 4);
  float* reprs      = (float*)alloc((size_t)NGRAPH * 128 * 4);
  int* gstart       = (int*)alloc((NGRAPH + 1) * 4);
  int* deg          = (int*)alloc((size_t)NNODES * 4);
  int* incl         = (int*)alloc((size_t)NNODES * 4);
  int* row_ptr      = (int*)alloc(((size_t)NNODES + 1) * 4);
  int* colv         = (int*)alloc((size_t)NEDGES * 4);
  int* blocksum     = (int*)alloc(512 * 4);
  unsigned short* wt_pre = (unsigned short*)alloc((size_t)128 * FIN * 2);
  unsigned short* wt1    = (unsigned short*)alloc((size_t)128 * HDIM * 2);
  unsigned short* wt2    = (unsigned short*)alloc((size_t)128 * HDIM * 2);
  int* blockHist    = (int*)alloc((size_t)EBLK * NBUCK * 4);
  int* blockBaseCol = (int*)alloc((size_t)NBUCK * EBLK * 4);
  int* bucket_total = (int*)alloc(NBUCK * 4);
  int* bucket_ptr   = (int*)alloc((NBUCK + 1) * 4);
  uint2* stagingG   = (uint2*)alloc((size_t)NEDGES * 8);

  int nb = (NNODES + 255) / 256;   // 391
  int wb = NNODES / 4;             // wave-per-node kernels: 256 thr = 4 waves
  int sb = (NNODES + SEG_CHUNK - 1) / SEG_CHUNK;
  int gb = (NNODES + 127) / 128;   // 782 GEMM blocks

  // one-shot weight conversion (bf16, transposed)
  convert_transpose<<<(FIN * 128 + 255) / 256, 256, 0, stream>>>(pre_w, wt_pre, FIN);
  convert_transpose<<<(HDIM * 128 + 255) / 256, 256, 0, stream>>>(w1, wt1, HDIM);
  convert_transpose<<<(HDIM * 128 + 255) / 256, 256, 0, stream>>>(w2, wt2, HDIM);

  // graph boundaries + zeroed pooling accumulator
  hipMemsetAsync(reprs, 0, (size_t)NGRAPH * 128 * 4, stream);
  find_starts<<<1, 256, 0, stream>>>(batch, gstart);

  // bucketed CSR build
  bin_count<<<EBLK, 256, 0, stream>>>(edst, blockHist);
  colscan<<<NBUCK, 512, 0, stream>>>(blockHist, blockBaseCol, bucket_total);
  bscan<<<1, 128, 0, stream>>>(bucket_total, bucket_ptr);
  bin_place<<<EBLK, 512, 0, stream>>>(esrc, edst, blockBaseCol, bucket_ptr, stagingG);
  bucket_deg<<<NBUCK, 1024, 0, stream>>>(stagingG, bucket_ptr, deg);
  scan_block<<<nb, 256, 0, stream>>>(deg, incl, blocksum);
  scan_offsets<<<1, 64, 0, stream>>>(blocksum, nb);
  finalize_csr<<<nb, 256, 0, stream>>>(deg, incl, blocksum, row_ptr);
  bucket_csr<<<NBUCK, 1024, 0, stream>>>(stagingG, bucket_ptr, row_ptr, colv);

  // pre layer: h0 = relu(x @ pre_w + pre_b)
  gemm_mfma<<<gb, 256, 0, stream>>>(x, wt_pre, pre_b, h, nullptr, NNODES, FIN, 1);
  seg_sum_fast<<<sb, 128, 0, stream>>>(h, batch, gstart, reprs);

  // GAT layer 1
  gemm_mfma<<<gb, 256, 0, stream>>>(h, wt1, nullptr, nullptr, hwb, NNODES, HDIM, 0);
  alpha_kernel<<<wb, 256, 0, stream>>>(hwb, asrc1, adst1, a_s, a_d);
  aggregate<<<wb, 256, 0, stream>>>(hwb, a_s, a_d, row_ptr, colv, b1, h);
  seg_sum_fast<<<sb, 128, 0, stream>>>(h, batch, gstart, reprs);

  // GAT layer 2
  gemm_mfma<<<gb, 256, 0, stream>>>(h, wt2, nullptr, nullptr, hwb, NNODES, HDIM, 0);
  alpha_kernel<<<wb, 256, 0, stream>>>(hwb, asrc2, adst2, a_s, a_d);
  aggregate<<<wb, 256, 0, stream>>>(hwb, a_s, a_d, row_ptr, colv, b2, h);
  seg_sum_fast<<<sb, 128, 0, stream>>>(h, batch, gstart, reprs);

  // head
  head_kernel<<<NGRAPH, 128, 0, stream>>>(reprs, pw1, pb1, pw2, pb2, out);
}

// Round 6
// 651.437 us; speedup vs baseline: 2.3416x; 1.0994x over previous
//
#include <hip/hip_runtime.h>
#include <hip/hip_bf16.h>
#include <math.h>

#define NNODES 100000
#define NEDGES 1600000
#define FIN 256
#define HDIM 128
#define NGRAPH 128
#define NCLS 10
#define NEG 0.2f

#define NBUCK 98            // buckets of 1024 dst nodes (100000 >> 10 -> 0..97)
#define EPB 4096            // edges per bin_place block
#define EBLK ((NEDGES + EPB - 1) / EPB)   // 391

typedef short bf8 __attribute__((ext_vector_type(8)));
typedef float f4 __attribute__((ext_vector_type(4)));

__device__ __forceinline__ float lrelu(float x) { return x > 0.f ? x : NEG * x; }

__device__ __forceinline__ unsigned short f2bf(float f) {
  union { float f; unsigned int u; } v; v.f = f;
  unsigned int r = v.u + 0x7fffu + ((v.u >> 16) & 1u);   // round-nearest-even
  return (unsigned short)(r >> 16);
}
__device__ __forceinline__ float bf_lo(unsigned int p) {
  union { unsigned int u; float f; } v; v.u = p << 16; return v.f;
}
__device__ __forceinline__ float bf_hi(unsigned int p) {
  union { unsigned int u; float f; } v; v.u = p & 0xffff0000u; return v.f;
}

// ---------------- one-shot weight convert+transpose: w[K][128] -> wt[128][K] -
__global__ __launch_bounds__(256) void convert_transpose(const float* __restrict__ w,
                                                         unsigned short* __restrict__ wt,
                                                         int K) {
  int i = blockIdx.x * 256 + threadIdx.x;
  if (i >= K * 128) return;
  int k = i >> 7, n = i & 127;
  wt[n * K + k] = f2bf(w[(size_t)k * 128 + n]);
}

// ---------------- MFMA GEMM ---------------------------------------------------
__global__ __launch_bounds__(256) void gemm_mfma(const float* __restrict__ A,
                                                 const unsigned short* __restrict__ Bt,
                                                 const float* __restrict__ bias,
                                                 float* __restrict__ C,
                                                 unsigned int* __restrict__ Cp,
                                                 int M, int K, int dorelu) {
  __shared__ bf8 As[512];
  __shared__ bf8 Bs[512];
  int tid = threadIdx.x;
  int wv = tid >> 6, lane = tid & 63;
  int quad = lane >> 4, m16 = lane & 15;
  int row0 = blockIdx.x * 128;

  f4 acc[2][8];
#pragma unroll
  for (int a = 0; a < 2; ++a)
#pragma unroll
    for (int b = 0; b < 8; ++b) acc[a][b] = (f4){0.f, 0.f, 0.f, 0.f};

  for (int kb = 0; kb < K; kb += 32) {
    __syncthreads();
#pragma unroll
    for (int bb = 0; bb < 2; ++bb) {
      int b = tid + bb * 256;
      int l = b & 63, mt = b >> 6;
      int row = row0 + mt * 16 + (l & 15);
      if (row > M - 1) row = M - 1;
      const float* src = &A[(size_t)row * K + kb + (l >> 4) * 8];
      float4 x0 = *reinterpret_cast<const float4*>(src);
      float4 x1 = *reinterpret_cast<const float4*>(src + 4);
      bf8 v;
      v[0] = (short)f2bf(x0.x); v[1] = (short)f2bf(x0.y);
      v[2] = (short)f2bf(x0.z); v[3] = (short)f2bf(x0.w);
      v[4] = (short)f2bf(x1.x); v[5] = (short)f2bf(x1.y);
      v[6] = (short)f2bf(x1.z); v[7] = (short)f2bf(x1.w);
      As[b] = v;
    }
#pragma unroll
    for (int bb = 0; bb < 2; ++bb) {
      int b = tid + bb * 256;
      int l = b & 63, tn = b >> 6;
      int n = tn * 16 + (l & 15);
      Bs[b] = *reinterpret_cast<const bf8*>(&Bt[(size_t)n * K + kb + (l >> 4) * 8]);
    }
    __syncthreads();
    bf8 af0 = As[(wv * 2 + 0) * 64 + lane];
    bf8 af1 = As[(wv * 2 + 1) * 64 + lane];
#pragma unroll
    for (int tn = 0; tn < 8; ++tn) {
      bf8 bfm = Bs[tn * 64 + lane];
      acc[0][tn] = __builtin_amdgcn_mfma_f32_16x16x32_bf16(af0, bfm, acc[0][tn], 0, 0, 0);
      acc[1][tn] = __builtin_amdgcn_mfma_f32_16x16x32_bf16(af1, bfm, acc[1][tn], 0, 0, 0);
    }
  }

  if (Cp) {
#pragma unroll
    for (int mt = 0; mt < 2; ++mt)
#pragma unroll
      for (int tn = 0; tn < 4; ++tn)
#pragma unroll
        for (int r = 0; r < 4; ++r) {
          int row = row0 + wv * 32 + mt * 16 + quad * 4 + r;
          if (row < M) {
            unsigned int p = (unsigned int)f2bf(acc[mt][tn][r]) |
                             ((unsigned int)f2bf(acc[mt][tn + 4][r]) << 16);
            Cp[(size_t)row * 64 + tn * 16 + m16] = p;
          }
        }
  } else {
#pragma unroll
    for (int mt = 0; mt < 2; ++mt)
#pragma unroll
      for (int tn = 0; tn < 8; ++tn) {
        float bv = bias ? bias[tn * 16 + m16] : 0.f;
#pragma unroll
        for (int r = 0; r < 4; ++r) {
          int row = row0 + wv * 32 + mt * 16 + quad * 4 + r;
          if (row < M) {
            float v = acc[mt][tn][r] + bv;
            if (dorelu) v = fmaxf(v, 0.f);
            C[(size_t)row * 128 + tn * 16 + m16] = v;
          }
        }
      }
  }
}

// ---------------- graph boundaries (batch is sorted) -------------------------
__global__ void find_starts(const int* __restrict__ batch, int* __restrict__ gstart) {
  int g = threadIdx.x;
  if (g > NGRAPH) return;
  if (g == NGRAPH) { gstart[g] = NNODES; return; }
  int lo = 0, hi = NNODES;
  while (lo < hi) { int mid = (lo + hi) >> 1; if (batch[mid] < g) lo = mid + 1; else hi = mid; }
  gstart[g] = lo;
}

// ======== CSR build, bucketed two-phase (no random global atomics) ==========
__global__ __launch_bounds__(256) void bin_count(const int* __restrict__ edst,
                                                 int* __restrict__ blockHist) {
  __shared__ int hist[NBUCK];
  int t = threadIdx.x, blk = blockIdx.x;
  if (t < NBUCK) hist[t] = 0;
  __syncthreads();
  int e0 = blk * EPB;
#pragma unroll
  for (int it = 0; it < EPB / 256; ++it) {
    int e = e0 + it * 256 + t;
    if (e < NEDGES) atomicAdd(&hist[((unsigned)edst[e]) >> 10], 1);
  }
  __syncthreads();
  if (t < NBUCK) blockHist[blk * NBUCK + t] = hist[t];
}

__global__ __launch_bounds__(512) void colscan(const int* __restrict__ blockHist,
                                               int* __restrict__ blockBaseCol,
                                               int* __restrict__ bucket_total) {
  __shared__ int s[512];
  int b = blockIdx.x, t = threadIdx.x;
  int v = (t < EBLK) ? blockHist[t * NBUCK + b] : 0;
  s[t] = v;
  __syncthreads();
  for (int off = 1; off < 512; off <<= 1) {
    int u = (t >= off) ? s[t - off] : 0;
    __syncthreads();
    s[t] += u;
    __syncthreads();
  }
  if (t < EBLK) blockBaseCol[b * EBLK + t] = s[t] - v;
  if (t == 511) bucket_total[b] = s[511];
}

__global__ __launch_bounds__(128) void bscan(const int* __restrict__ bucket_total,
                                             int* __restrict__ bucket_ptr) {
  __shared__ int s[128];
  int t = threadIdx.x;
  int v = (t < NBUCK) ? bucket_total[t] : 0;
  s[t] = v;
  __syncthreads();
  for (int off = 1; off < 128; off <<= 1) {
    int u = (t >= off) ? s[t - off] : 0;
    __syncthreads();
    s[t] += u;
    __syncthreads();
  }
  if (t < NBUCK) bucket_ptr[t] = s[t] - v;
  if (t == 127) bucket_ptr[NBUCK] = s[127];
}

__global__ __launch_bounds__(512) void bin_place(const int* __restrict__ esrc,
                                                 const int* __restrict__ edst,
                                                 const int* __restrict__ blockBaseCol,
                                                 const int* __restrict__ bucket_ptr,
                                                 uint2* __restrict__ stagingG) {
  __shared__ int hist[NBUCK + 1], lbase[NBUCK + 1], lcur[NBUCK + 1], cbase[NBUCK];
  __shared__ int tmp[128];
  __shared__ uint2 st[EPB];
  int t = threadIdx.x, blk = blockIdx.x;
  if (t < NBUCK + 1) hist[t] = 0;
  __syncthreads();
  int e0 = blk * EPB;
#pragma unroll
  for (int it = 0; it < EPB / 512; ++it) {
    int e = e0 + it * 512 + t;
    int b = NBUCK;
    if (e < NEDGES) b = ((unsigned)edst[e]) >> 10;
    atomicAdd(&hist[b], 1);
  }
  __syncthreads();
  if (t < 128) tmp[t] = (t < NBUCK + 1) ? hist[t] : 0;
  __syncthreads();
  for (int off = 1; off < 128; off <<= 1) {
    int u = 0;
    if (t < 128 && t >= off) u = tmp[t - off];
    __syncthreads();
    if (t < 128) tmp[t] += u;
    __syncthreads();
  }
  if (t < NBUCK + 1) { int ex = tmp[t] - hist[t]; lbase[t] = ex; lcur[t] = ex; }
  if (t < NBUCK) cbase[t] = bucket_ptr[t] + blockBaseCol[t * EBLK + blk];
  __syncthreads();
#pragma unroll
  for (int it = 0; it < EPB / 512; ++it) {
    int e = e0 + it * 512 + t;
    unsigned s = 0, d = 0xFFFFFFFFu;
    if (e < NEDGES) { s = (unsigned)esrc[e]; d = (unsigned)edst[e]; }
    int b = (d == 0xFFFFFFFFu) ? NBUCK : (int)(d >> 10);
    int slot = atomicAdd(&lcur[b], 1);
    st[slot] = make_uint2(s, d);
  }
  __syncthreads();
  for (int i = t; i < EPB; i += 512) {
    uint2 ed = st[i];
    if (ed.y == 0xFFFFFFFFu) continue;
    int b = (int)(ed.y >> 10);
    stagingG[cbase[b] + (i - lbase[b])] = ed;
  }
}

__global__ __launch_bounds__(1024) void bucket_deg(const uint2* __restrict__ stagingG,
                                                   const int* __restrict__ bucket_ptr,
                                                   int* __restrict__ deg) {
  __shared__ int dl[1024];
  int b = blockIdx.x, t = threadIdx.x;
  dl[t] = 0;
  __syncthreads();
  int s0 = bucket_ptr[b], s1 = bucket_ptr[b + 1];
  for (int j = s0 + t; j < s1; j += 1024)
    atomicAdd(&dl[stagingG[j].y & 1023], 1);
  __syncthreads();
  int n = (b << 10) + t;
  if (n < NNODES) deg[n] = dl[t];
}

__global__ __launch_bounds__(256) void scan_block(const int* __restrict__ deg,
                                                  int* __restrict__ incl,
                                                  int* __restrict__ blocksum) {
  __shared__ int s[256];
  int tid = threadIdx.x;
  int i = blockIdx.x * 256 + tid;
  s[tid] = (i < NNODES) ? deg[i] : 0;
  __syncthreads();
  for (int off = 1; off < 256; off <<= 1) {
    int t = (tid >= off) ? s[tid - off] : 0;
    __syncthreads();
    s[tid] += t;
    __syncthreads();
  }
  if (i < NNODES) incl[i] = s[tid];
  if (tid == 255) blocksum[blockIdx.x] = s[255];
}

__global__ void scan_offsets(int* blocksum, int nb) {
  if (threadIdx.x == 0 && blockIdx.x == 0) {
    int run = 0;
    for (int b = 0; b < nb; ++b) { int t = blocksum[b]; blocksum[b] = run; run += t; }
  }
}

__global__ __launch_bounds__(256) void finalize_csr(const int* __restrict__ deg,
                                                    const int* __restrict__ incl,
                                                    const int* __restrict__ blocksum,
                                                    int* __restrict__ row_ptr) {
  int i = blockIdx.x * 256 + threadIdx.x;
  if (i >= NNODES) return;
  int tot = incl[i] + blocksum[i >> 8];
  row_ptr[i] = tot - deg[i];
  if (i == NNODES - 1) row_ptr[NNODES] = tot;
}

__global__ __launch_bounds__(1024) void bucket_csr(const uint2* __restrict__ stagingG,
                                                   const int* __restrict__ bucket_ptr,
                                                   const int* __restrict__ row_ptr,
                                                   int* __restrict__ colv) {
  __shared__ int cur[1024];
  int b = blockIdx.x, t = threadIdx.x;
  int n = (b << 10) + t;
  cur[t] = (n < NNODES) ? row_ptr[n] : 0;
  __syncthreads();
  int s0 = bucket_ptr[b], s1 = bucket_ptr[b + 1];
  for (int j = s0 + t; j < s1; j += 1024) {
    uint2 e = stagingG[j];
    int pos = atomicAdd(&cur[e.y & 1023], 1);
    colv[pos] = (int)e.x;
  }
}

// ---------------- per-node attention logits (packed bf16 input) --------------
__global__ __launch_bounds__(256) void alpha_kernel(const unsigned int* __restrict__ hwb,
                                                    const float* __restrict__ aw_src,
                                                    const float* __restrict__ aw_dst,
                                                    float* __restrict__ a_s,
                                                    float* __restrict__ a_d) {
  int wid = (blockIdx.x * 256 + threadIdx.x) >> 6;
  int lane = threadIdx.x & 63;
  if (wid >= NNODES) return;
  unsigned int p = hwb[(size_t)wid * 64 + lane];
  float v0 = bf_lo(p), v1 = bf_hi(p);
  float s0 = v0 * aw_src[lane], s1 = v1 * aw_src[64 + lane];
  float d0 = v0 * aw_dst[lane], d1 = v1 * aw_dst[64 + lane];
  for (int o = 32; o; o >>= 1) {
    s0 += __shfl_xor(s0, o); s1 += __shfl_xor(s1, o);
    d0 += __shfl_xor(d0, o); d1 += __shfl_xor(d1, o);
  }
  if (lane == 0) {
    a_s[2 * wid] = s0; a_s[2 * wid + 1] = s1;
    a_d[2 * wid] = d0; a_d[2 * wid + 1] = d1;
  }
}

// ---------------- softmax aggregation: one wave per dst node -----------------
// Gather loop unrolled x8 with ghost-edge padding: lanes >= deg carry w=0 and
// sl=0, so padded iterations load the L1-hot hwb[0] row and FMA by zero.
__global__ __launch_bounds__(256) void aggregate(const unsigned int* __restrict__ hwb,
                                                 const float* __restrict__ a_s,
                                                 const float* __restrict__ a_d,
                                                 const int* __restrict__ row_ptr,
                                                 const int* __restrict__ colv,
                                                 const float* __restrict__ bias,
                                                 float* __restrict__ out) {
  int i = (blockIdx.x * 256 + threadIdx.x) >> 6;
  int lane = threadIdx.x & 63;
  if (i >= NNODES) return;
  float ad0 = a_d[2 * i], ad1 = a_d[2 * i + 1];
  float es0 = lrelu(a_s[2 * i] + ad0), es1 = lrelu(a_s[2 * i + 1] + ad1);  // self edge
  int start = row_ptr[i], end = row_ptr[i + 1];
  int deg = end - start;

  int sl = 0; float e0l = -1e30f, e1l = -1e30f;
  if (lane < deg) {
    sl = colv[start + lane];
    float2 av = *reinterpret_cast<const float2*>(&a_s[2 * sl]);
    e0l = lrelu(av.x + ad0); e1l = lrelu(av.y + ad1);
  }
  float m0 = fmaxf(es0, e0l), m1 = fmaxf(es1, e1l);
  for (int j = start + 64 + lane; j < end; j += 64) {
    int s = colv[j];
    float2 av = *reinterpret_cast<const float2*>(&a_s[2 * s]);
    m0 = fmaxf(m0, lrelu(av.x + ad0));
    m1 = fmaxf(m1, lrelu(av.y + ad1));
  }
  for (int o = 32; o; o >>= 1) {
    m0 = fmaxf(m0, __shfl_xor(m0, o));
    m1 = fmaxf(m1, __shfl_xor(m1, o));
  }
  float w0l = lane < deg ? __expf(e0l - m0) : 0.f;
  float w1l = lane < deg ? __expf(e1l - m1) : 0.f;
  float d0 = w0l, d1 = w1l;
  for (int o = 32; o; o >>= 1) { d0 += __shfl_xor(d0, o); d1 += __shfl_xor(d1, o); }
  float ws0 = __expf(es0 - m0), ws1 = __expf(es1 - m1);
  float den0 = d0 + ws0, den1 = d1 + ws1;

  unsigned int ps = hwb[(size_t)i * 64 + lane];
  float acc0 = ws0 * bf_lo(ps), acc1 = ws1 * bf_hi(ps);
  int dmin = deg < 64 ? deg : 64;
  int dpad = (dmin + 7) & ~7;   // ghost-pad to x8 (w=0, sl=0 on ghost lanes)
  for (int t = 0; t < dpad; t += 8) {
    int s0 = __shfl(sl, t),     s1 = __shfl(sl, t + 1);
    int s2 = __shfl(sl, t + 2), s3 = __shfl(sl, t + 3);
    int s4 = __shfl(sl, t + 4), s5 = __shfl(sl, t + 5);
    int s6 = __shfl(sl, t + 6), s7 = __shfl(sl, t + 7);
    unsigned q0 = hwb[(size_t)s0 * 64 + lane];
    unsigned q1 = hwb[(size_t)s1 * 64 + lane];
    unsigned q2 = hwb[(size_t)s2 * 64 + lane];
    unsigned q3 = hwb[(size_t)s3 * 64 + lane];
    unsigned q4 = hwb[(size_t)s4 * 64 + lane];
    unsigned q5 = hwb[(size_t)s5 * 64 + lane];
    unsigned q6 = hwb[(size_t)s6 * 64 + lane];
    unsigned q7 = hwb[(size_t)s7 * 64 + lane];
    float wa0 = __shfl(w0l, t),     wb0 = __shfl(w1l, t);
    float wa1 = __shfl(w0l, t + 1), wb1 = __shfl(w1l, t + 1);
    float wa2 = __shfl(w0l, t + 2), wb2 = __shfl(w1l, t + 2);
    float wa3 = __shfl(w0l, t + 3), wb3 = __shfl(w1l, t + 3);
    float wa4 = __shfl(w0l, t + 4), wb4 = __shfl(w1l, t + 4);
    float wa5 = __shfl(w0l, t + 5), wb5 = __shfl(w1l, t + 5);
    float wa6 = __shfl(w0l, t + 6), wb6 = __shfl(w1l, t + 6);
    float wa7 = __shfl(w0l, t + 7), wb7 = __shfl(w1l, t + 7);
    acc0 = fmaf(wa0, bf_lo(q0), acc0); acc1 = fmaf(wb0, bf_hi(q0), acc1);
    acc0 = fmaf(wa1, bf_lo(q1), acc0); acc1 = fmaf(wb1, bf_hi(q1), acc1);
    acc0 = fmaf(wa2, bf_lo(q2), acc0); acc1 = fmaf(wb2, bf_hi(q2), acc1);
    acc0 = fmaf(wa3, bf_lo(q3), acc0); acc1 = fmaf(wb3, bf_hi(q3), acc1);
    acc0 = fmaf(wa4, bf_lo(q4), acc0); acc1 = fmaf(wb4, bf_hi(q4), acc1);
    acc0 = fmaf(wa5, bf_lo(q5), acc0); acc1 = fmaf(wb5, bf_hi(q5), acc1);
    acc0 = fmaf(wa6, bf_lo(q6), acc0); acc1 = fmaf(wb6, bf_hi(q6), acc1);
    acc0 = fmaf(wa7, bf_lo(q7), acc0); acc1 = fmaf(wb7, bf_hi(q7), acc1);
  }
  for (int j = start + 64; j < end; ++j) {   // rare overflow path (deg > 64)
    int s = colv[j];
    float2 av = *reinterpret_cast<const float2*>(&a_s[2 * s]);
    float w0 = __expf(lrelu(av.x + ad0) - m0);
    float w1 = __expf(lrelu(av.y + ad1) - m1);
    den0 += w0; den1 += w1;
    unsigned int q = hwb[(size_t)s * 64 + lane];
    acc0 = fmaf(w0, bf_lo(q), acc0);
    acc1 = fmaf(w1, bf_hi(q), acc1);
  }
  out[(size_t)i * 128 + lane]      = fmaxf(acc0 / den0 + bias[lane], 0.f);
  out[(size_t)i * 128 + 64 + lane] = fmaxf(acc1 / den1 + bias[64 + lane], 0.f);
}

// ---------------- per-graph pooling, node-parallel ---------------------------
#define SEG_CHUNK 128
__global__ __launch_bounds__(128) void seg_sum_fast(const float* __restrict__ h,
                                                    const int* __restrict__ batch,
                                                    const int* __restrict__ gstart,
                                                    float* __restrict__ reprs) {
  int n0 = blockIdx.x * SEG_CHUNK;
  if (n0 >= NNODES) return;
  int nend = n0 + SEG_CHUNK; if (nend > NNODES) nend = NNODES;
  int tid = threadIdx.x;
  int r = n0;
  while (r < nend) {
    int g = batch[r];
    int segend = gstart[g + 1]; if (segend > nend) segend = nend;
    float a0 = 0.f, a1 = 0.f, a2 = 0.f, a3 = 0.f;
    for (; r + 3 < segend; r += 4) {
      a0 += h[(size_t)r * 128 + tid];
      a1 += h[(size_t)(r + 1) * 128 + tid];
      a2 += h[(size_t)(r + 2) * 128 + tid];
      a3 += h[(size_t)(r + 3) * 128 + tid];
    }
    for (; r < segend; ++r) a0 += h[(size_t)r * 128 + tid];
    atomicAdd(&reprs[g * 128 + tid], (a0 + a1) + (a2 + a3));
  }
}

// ---------------- head MLP + log_softmax -------------------------------------
__global__ __launch_bounds__(128) void head_kernel(const float* __restrict__ reprs,
                                                   const float* __restrict__ pw1,
                                                   const float* __restrict__ pb1,
                                                   const float* __restrict__ pw2,
                                                   const float* __restrict__ pb2,
                                                   float* __restrict__ out) {
  __shared__ float r[128], t1[128], z[NCLS];
  int g = blockIdx.x, tid = threadIdx.x;
  r[tid] = reprs[g * 128 + tid];
  __syncthreads();
  float acc = pb1[tid];
  for (int k = 0; k < 128; ++k) acc = fmaf(r[k], pw1[k * 128 + tid], acc);
  t1[tid] = fmaxf(acc, 0.f);
  __syncthreads();
  if (tid < NCLS) {
    float zz = pb2[tid];
    for (int k = 0; k < 128; ++k) zz = fmaf(t1[k], pw2[k * NCLS + tid], zz);
    z[tid] = zz;
  }
  __syncthreads();
  if (tid == 0) {
    float mx = -1e30f;
    for (int c = 0; c < NCLS; ++c) mx = fmaxf(mx, z[c]);
    float s = 0.f;
    for (int c = 0; c < NCLS; ++c) s += expf(z[c] - mx);
    float ls = logf(s) + mx;
    for (int c = 0; c < NCLS; ++c) out[g * NCLS + c] = z[c] - ls;
  }
}

extern "C" void kernel_launch(void* const* d_in, const int* in_sizes, int n_in,
                              void* d_out, int out_size, void* d_ws, size_t ws_size,
                              hipStream_t stream) {
  const float* x     = (const float*)d_in[0];
  const int*   eidx  = (const int*)d_in[1];
  const int*   batch = (const int*)d_in[2];
  const float* pre_w = (const float*)d_in[3];
  const float* pre_b = (const float*)d_in[4];
  const float* w1    = (const float*)d_in[5];
  const float* asrc1 = (const float*)d_in[6];
  const float* adst1 = (const float*)d_in[7];
  const float* b1    = (const float*)d_in[8];
  const float* w2    = (const float*)d_in[9];
  const float* asrc2 = (const float*)d_in[10];
  const float* adst2 = (const float*)d_in[11];
  const float* b2    = (const float*)d_in[12];
  const float* pw1   = (const float*)d_in[13];
  const float* pb1   = (const float*)d_in[14];
  const float* pw2   = (const float*)d_in[15];
  const float* pb2   = (const float*)d_in[16];
  float* out = (float*)d_out;

  const int* esrc = eidx;
  const int* edst = eidx + NEDGES;

  char* wsp = (char*)d_ws;
  size_t off = 0;
  auto alloc = [&](size_t bytes) -> void* {
    void* p = wsp + off;
    off += (bytes + 255) & ~(size_t)255;
    return p;
  };
  float* h          = (float*)alloc((size_t)NNODES * 128 * 4);
  unsigned int* hwb = (unsigned int*)alloc((size_t)NNODES * 64 * 4);
  float* a_s        = (float*)alloc((size_t)NNODES * 2 * 4);
  float* a_d        = (float*)alloc((size_t)NNODES * 2 * 4);
  float* reprs      = (float*)alloc((size_t)NGRAPH * 128 * 4);
  int* gstart       = (int*)alloc((NGRAPH + 1) * 4);
  int* deg          = (int*)alloc((size_t)NNODES * 4);
  int* incl         = (int*)alloc((size_t)NNODES * 4);
  int* row_ptr      = (int*)alloc(((size_t)NNODES + 1) * 4);
  int* colv         = (int*)alloc((size_t)NEDGES * 4);
  int* blocksum     = (int*)alloc(512 * 4);
  unsigned short* wt_pre = (unsigned short*)alloc((size_t)128 * FIN * 2);
  unsigned short* wt1    = (unsigned short*)alloc((size_t)128 * HDIM * 2);
  unsigned short* wt2    = (unsigned short*)alloc((size_t)128 * HDIM * 2);
  int* blockHist    = (int*)alloc((size_t)EBLK * NBUCK * 4);
  int* blockBaseCol = (int*)alloc((size_t)NBUCK * EBLK * 4);
  int* bucket_total = (int*)alloc(NBUCK * 4);
  int* bucket_ptr   = (int*)alloc((NBUCK + 1) * 4);
  uint2* stagingG   = (uint2*)alloc((size_t)NEDGES * 8);

  int nb = (NNODES + 255) / 256;   // 391
  int wb = NNODES / 4;             // wave-per-node kernels: 256 thr = 4 waves
  int sb = (NNODES + SEG_CHUNK - 1) / SEG_CHUNK;
  int gb = (NNODES + 127) / 128;   // 782 GEMM blocks

  // one-shot weight conversion (bf16, transposed)
  convert_transpose<<<(FIN * 128 + 255) / 256, 256, 0, stream>>>(pre_w, wt_pre, FIN);
  convert_transpose<<<(HDIM * 128 + 255) / 256, 256, 0, stream>>>(w1, wt1, HDIM);
  convert_transpose<<<(HDIM * 128 + 255) / 256, 256, 0, stream>>>(w2, wt2, HDIM);

  // graph boundaries + zeroed pooling accumulator
  hipMemsetAsync(reprs, 0, (size_t)NGRAPH * 128 * 4, stream);
  find_starts<<<1, 256, 0, stream>>>(batch, gstart);

  // bucketed CSR build
  bin_count<<<EBLK, 256, 0, stream>>>(edst, blockHist);
  colscan<<<NBUCK, 512, 0, stream>>>(blockHist, blockBaseCol, bucket_total);
  bscan<<<1, 128, 0, stream>>>(bucket_total, bucket_ptr);
  bin_place<<<EBLK, 512, 0, stream>>>(esrc, edst, blockBaseCol, bucket_ptr, stagingG);
  bucket_deg<<<NBUCK, 1024, 0, stream>>>(stagingG, bucket_ptr, deg);
  scan_block<<<nb, 256, 0, stream>>>(deg, incl, blocksum);
  scan_offsets<<<1, 64, 0, stream>>>(blocksum, nb);
  finalize_csr<<<nb, 256, 0, stream>>>(deg, incl, blocksum, row_ptr);
  bucket_csr<<<NBUCK, 1024, 0, stream>>>(stagingG, bucket_ptr, row_ptr, colv);

  // pre layer: h0 = relu(x @ pre_w + pre_b)
  gemm_mfma<<<gb, 256, 0, stream>>>(x, wt_pre, pre_b, h, nullptr, NNODES, FIN, 1);
  seg_sum_fast<<<sb, 128, 0, stream>>>(h, batch, gstart, reprs);

  // GAT layer 1
  gemm_mfma<<<gb, 256, 0, stream>>>(h, wt1, nullptr, nullptr, hwb, NNODES, HDIM, 0);
  alpha_kernel<<<wb, 256, 0, stream>>>(hwb, asrc1, adst1, a_s, a_d);
  aggregate<<<wb, 256, 0, stream>>>(hwb, a_s, a_d, row_ptr, colv, b1, h);
  seg_sum_fast<<<sb, 128, 0, stream>>>(h, batch, gstart, reprs);

  // GAT layer 2
  gemm_mfma<<<gb, 256, 0, stream>>>(h, wt2, nullptr, nullptr, hwb, NNODES, HDIM, 0);
  alpha_kernel<<<wb, 256, 0, stream>>>(hwb, asrc2, adst2, a_s, a_d);
  aggregate<<<wb, 256, 0, stream>>>(hwb, a_s, a_d, row_ptr, colv, b2, h);
  seg_sum_fast<<<sb, 128, 0, stream>>>(h, batch, gstart, reprs);

  // head
  head_kernel<<<NGRAPH, 128, 0, stream>>>(reprs, pw1, pb1, pw2, pb2, out);
}

// Round 7
// 572.859 us; speedup vs baseline: 2.6627x; 1.1372x over previous
//
#include <hip/hip_runtime.h>
#include <hip/hip_bf16.h>
#include <math.h>

#define NNODES 100000
#define NEDGES 1600000
#define FIN 256
#define HDIM 128
#define NGRAPH 128
#define NCLS 10
#define NEG 0.2f

#define NBUCK 98            // buckets of 1024 dst nodes (100000 >> 10 -> 0..97)
#define EPB 4096            // edges per bin_place block
#define EBLK ((NEDGES + EPB - 1) / EPB)   // 391

typedef short bf8 __attribute__((ext_vector_type(8)));
typedef float f4 __attribute__((ext_vector_type(4)));

__device__ __forceinline__ float lrelu(float x) { return x > 0.f ? x : NEG * x; }

__device__ __forceinline__ unsigned short f2bf(float f) {
  union { float f; unsigned int u; } v; v.f = f;
  unsigned int r = v.u + 0x7fffu + ((v.u >> 16) & 1u);   // round-nearest-even
  return (unsigned short)(r >> 16);
}
__device__ __forceinline__ float bf_lo(unsigned int p) {
  union { unsigned int u; float f; } v; v.u = p << 16; return v.f;
}
__device__ __forceinline__ float bf_hi(unsigned int p) {
  union { unsigned int u; float f; } v; v.u = p & 0xffff0000u; return v.f;
}

// ---------------- one-shot weight convert+transpose: w[K][128] -> wt[128][K] -
__global__ __launch_bounds__(256) void convert_transpose(const float* __restrict__ w,
                                                         unsigned short* __restrict__ wt,
                                                         int K) {
  int i = blockIdx.x * 256 + threadIdx.x;
  if (i >= K * 128) return;
  int k = i >> 7, n = i & 127;
  wt[n * K + k] = f2bf(w[(size_t)k * 128 + n]);
}

// ---------------- MFMA GEMM (+ optional fused attention-logit epilogue) ------
// 256 thr = 4 waves; block tile 128 rows x 128 cols; wave tile 32 x 128.
// If Cp != null: packed bf16 output + (if a_src) fused per-node logits.
__global__ __launch_bounds__(256) void gemm_mfma(const float* __restrict__ A,
                                                 const unsigned short* __restrict__ Bt,
                                                 const float* __restrict__ bias,
                                                 float* __restrict__ C,
                                                 unsigned int* __restrict__ Cp,
                                                 const float* __restrict__ a_src,
                                                 const float* __restrict__ a_dst,
                                                 float* __restrict__ o_as,
                                                 float* __restrict__ o_ad,
                                                 int M, int K, int dorelu) {
  __shared__ bf8 As[512];
  __shared__ bf8 Bs[512];
  int tid = threadIdx.x;
  int wv = tid >> 6, lane = tid & 63;
  int quad = lane >> 4, m16 = lane & 15;
  int row0 = blockIdx.x * 128;

  f4 acc[2][8];
#pragma unroll
  for (int a = 0; a < 2; ++a)
#pragma unroll
    for (int b = 0; b < 8; ++b) acc[a][b] = (f4){0.f, 0.f, 0.f, 0.f};

  for (int kb = 0; kb < K; kb += 32) {
    __syncthreads();
#pragma unroll
    for (int bb = 0; bb < 2; ++bb) {
      int b = tid + bb * 256;
      int l = b & 63, mt = b >> 6;
      int row = row0 + mt * 16 + (l & 15);
      if (row > M - 1) row = M - 1;
      const float* src = &A[(size_t)row * K + kb + (l >> 4) * 8];
      float4 x0 = *reinterpret_cast<const float4*>(src);
      float4 x1 = *reinterpret_cast<const float4*>(src + 4);
      bf8 v;
      v[0] = (short)f2bf(x0.x); v[1] = (short)f2bf(x0.y);
      v[2] = (short)f2bf(x0.z); v[3] = (short)f2bf(x0.w);
      v[4] = (short)f2bf(x1.x); v[5] = (short)f2bf(x1.y);
      v[6] = (short)f2bf(x1.z); v[7] = (short)f2bf(x1.w);
      As[b] = v;
    }
#pragma unroll
    for (int bb = 0; bb < 2; ++bb) {
      int b = tid + bb * 256;
      int l = b & 63, tn = b >> 6;
      int n = tn * 16 + (l & 15);
      Bs[b] = *reinterpret_cast<const bf8*>(&Bt[(size_t)n * K + kb + (l >> 4) * 8]);
    }
    __syncthreads();
    bf8 af0 = As[(wv * 2 + 0) * 64 + lane];
    bf8 af1 = As[(wv * 2 + 1) * 64 + lane];
#pragma unroll
    for (int tn = 0; tn < 8; ++tn) {
      bf8 bfm = Bs[tn * 64 + lane];
      acc[0][tn] = __builtin_amdgcn_mfma_f32_16x16x32_bf16(af0, bfm, acc[0][tn], 0, 0, 0);
      acc[1][tn] = __builtin_amdgcn_mfma_f32_16x16x32_bf16(af1, bfm, acc[1][tn], 0, 0, 0);
    }
  }

  if (Cp) {
    // fused attention logits: per row, s_h = sum_c hw[row][c]*a[c] per head
    if (a_src) {
      float aS[8], aD[8];
#pragma unroll
      for (int tn = 0; tn < 4; ++tn) {
        aS[tn]     = a_src[tn * 16 + m16];       // head0 channels
        aS[tn + 4] = a_src[64 + tn * 16 + m16];  // head1 channels
        aD[tn]     = a_dst[tn * 16 + m16];
        aD[tn + 4] = a_dst[64 + tn * 16 + m16];
      }
#pragma unroll
      for (int mt = 0; mt < 2; ++mt)
#pragma unroll
        for (int r = 0; r < 4; ++r) {
          int row = row0 + wv * 32 + mt * 16 + quad * 4 + r;
          float ps0 = 0.f, ps1 = 0.f, pd0 = 0.f, pd1 = 0.f;
#pragma unroll
          for (int tn = 0; tn < 4; ++tn) {
            float v0 = acc[mt][tn][r], v1 = acc[mt][tn + 4][r];
            ps0 = fmaf(v0, aS[tn], ps0);
            ps1 = fmaf(v1, aS[tn + 4], ps1);
            pd0 = fmaf(v0, aD[tn], pd0);
            pd1 = fmaf(v1, aD[tn + 4], pd1);
          }
#pragma unroll
          for (int o = 8; o; o >>= 1) {
            ps0 += __shfl_xor(ps0, o); ps1 += __shfl_xor(ps1, o);
            pd0 += __shfl_xor(pd0, o); pd1 += __shfl_xor(pd1, o);
          }
          if (m16 == 0 && row < M) {
            o_as[2 * row] = ps0; o_as[2 * row + 1] = ps1;
            o_ad[2 * row] = pd0; o_ad[2 * row + 1] = pd1;
          }
        }
    }
#pragma unroll
    for (int mt = 0; mt < 2; ++mt)
#pragma unroll
      for (int tn = 0; tn < 4; ++tn)
#pragma unroll
        for (int r = 0; r < 4; ++r) {
          int row = row0 + wv * 32 + mt * 16 + quad * 4 + r;
          if (row < M) {
            unsigned int p = (unsigned int)f2bf(acc[mt][tn][r]) |
                             ((unsigned int)f2bf(acc[mt][tn + 4][r]) << 16);
            Cp[(size_t)row * 64 + tn * 16 + m16] = p;
          }
        }
  } else {
#pragma unroll
    for (int mt = 0; mt < 2; ++mt)
#pragma unroll
      for (int tn = 0; tn < 8; ++tn) {
        float bv = bias ? bias[tn * 16 + m16] : 0.f;
#pragma unroll
        for (int r = 0; r < 4; ++r) {
          int row = row0 + wv * 32 + mt * 16 + quad * 4 + r;
          if (row < M) {
            float v = acc[mt][tn][r] + bv;
            if (dorelu) v = fmaxf(v, 0.f);
            C[(size_t)row * 128 + tn * 16 + m16] = v;
          }
        }
      }
  }
}

// ---------------- graph boundaries (batch is sorted) -------------------------
__global__ void find_starts(const int* __restrict__ batch, int* __restrict__ gstart) {
  int g = threadIdx.x;
  if (g > NGRAPH) return;
  if (g == NGRAPH) { gstart[g] = NNODES; return; }
  int lo = 0, hi = NNODES;
  while (lo < hi) { int mid = (lo + hi) >> 1; if (batch[mid] < g) lo = mid + 1; else hi = mid; }
  gstart[g] = lo;
}

// ======== CSR build, bucketed two-phase (no random global atomics) ==========
__global__ __launch_bounds__(256) void bin_count(const int* __restrict__ edst,
                                                 int* __restrict__ blockHist) {
  __shared__ int hist[NBUCK];
  int t = threadIdx.x, blk = blockIdx.x;
  if (t < NBUCK) hist[t] = 0;
  __syncthreads();
  int e0 = blk * EPB;
#pragma unroll
  for (int it = 0; it < EPB / 256; ++it) {
    int e = e0 + it * 256 + t;
    if (e < NEDGES) atomicAdd(&hist[((unsigned)edst[e]) >> 10], 1);
  }
  __syncthreads();
  if (t < NBUCK) blockHist[blk * NBUCK + t] = hist[t];
}

__global__ __launch_bounds__(512) void colscan(const int* __restrict__ blockHist,
                                               int* __restrict__ blockBaseCol,
                                               int* __restrict__ bucket_total) {
  __shared__ int s[512];
  int b = blockIdx.x, t = threadIdx.x;
  int v = (t < EBLK) ? blockHist[t * NBUCK + b] : 0;
  s[t] = v;
  __syncthreads();
  for (int off = 1; off < 512; off <<= 1) {
    int u = (t >= off) ? s[t - off] : 0;
    __syncthreads();
    s[t] += u;
    __syncthreads();
  }
  if (t < EBLK) blockBaseCol[b * EBLK + t] = s[t] - v;
  if (t == 511) bucket_total[b] = s[511];
}

__global__ __launch_bounds__(128) void bscan(const int* __restrict__ bucket_total,
                                             int* __restrict__ bucket_ptr) {
  __shared__ int s[128];
  int t = threadIdx.x;
  int v = (t < NBUCK) ? bucket_total[t] : 0;
  s[t] = v;
  __syncthreads();
  for (int off = 1; off < 128; off <<= 1) {
    int u = (t >= off) ? s[t - off] : 0;
    __syncthreads();
    s[t] += u;
    __syncthreads();
  }
  if (t < NBUCK) bucket_ptr[t] = s[t] - v;
  if (t == 127) bucket_ptr[NBUCK] = s[127];
}

__global__ __launch_bounds__(512) void bin_place(const int* __restrict__ esrc,
                                                 const int* __restrict__ edst,
                                                 const int* __restrict__ blockBaseCol,
                                                 const int* __restrict__ bucket_ptr,
                                                 uint2* __restrict__ stagingG) {
  __shared__ int hist[NBUCK + 1], lbase[NBUCK + 1], lcur[NBUCK + 1], cbase[NBUCK];
  __shared__ int tmp[128];
  __shared__ uint2 st[EPB];
  int t = threadIdx.x, blk = blockIdx.x;
  if (t < NBUCK + 1) hist[t] = 0;
  __syncthreads();
  int e0 = blk * EPB;
#pragma unroll
  for (int it = 0; it < EPB / 512; ++it) {
    int e = e0 + it * 512 + t;
    int b = NBUCK;
    if (e < NEDGES) b = ((unsigned)edst[e]) >> 10;
    atomicAdd(&hist[b], 1);
  }
  __syncthreads();
  if (t < 128) tmp[t] = (t < NBUCK + 1) ? hist[t] : 0;
  __syncthreads();
  for (int off = 1; off < 128; off <<= 1) {
    int u = 0;
    if (t < 128 && t >= off) u = tmp[t - off];
    __syncthreads();
    if (t < 128) tmp[t] += u;
    __syncthreads();
  }
  if (t < NBUCK + 1) { int ex = tmp[t] - hist[t]; lbase[t] = ex; lcur[t] = ex; }
  if (t < NBUCK) cbase[t] = bucket_ptr[t] + blockBaseCol[t * EBLK + blk];
  __syncthreads();
#pragma unroll
  for (int it = 0; it < EPB / 512; ++it) {
    int e = e0 + it * 512 + t;
    unsigned s = 0, d = 0xFFFFFFFFu;
    if (e < NEDGES) { s = (unsigned)esrc[e]; d = (unsigned)edst[e]; }
    int b = (d == 0xFFFFFFFFu) ? NBUCK : (int)(d >> 10);
    int slot = atomicAdd(&lcur[b], 1);
    st[slot] = make_uint2(s, d);
  }
  __syncthreads();
  for (int i = t; i < EPB; i += 512) {
    uint2 ed = st[i];
    if (ed.y == 0xFFFFFFFFu) continue;
    int b = (int)(ed.y >> 10);
    stagingG[cbase[b] + (i - lbase[b])] = ed;
  }
}

__global__ __launch_bounds__(1024) void bucket_deg(const uint2* __restrict__ stagingG,
                                                   const int* __restrict__ bucket_ptr,
                                                   int* __restrict__ deg) {
  __shared__ int dl[1024];
  int b = blockIdx.x, t = threadIdx.x;
  dl[t] = 0;
  __syncthreads();
  int s0 = bucket_ptr[b], s1 = bucket_ptr[b + 1];
  for (int j = s0 + t; j < s1; j += 1024)
    atomicAdd(&dl[stagingG[j].y & 1023], 1);
  __syncthreads();
  int n = (b << 10) + t;
  if (n < NNODES) deg[n] = dl[t];
}

__global__ __launch_bounds__(256) void scan_block(const int* __restrict__ deg,
                                                  int* __restrict__ incl,
                                                  int* __restrict__ blocksum) {
  __shared__ int s[256];
  int tid = threadIdx.x;
  int i = blockIdx.x * 256 + tid;
  s[tid] = (i < NNODES) ? deg[i] : 0;
  __syncthreads();
  for (int off = 1; off < 256; off <<= 1) {
    int t = (tid >= off) ? s[tid - off] : 0;
    __syncthreads();
    s[tid] += t;
    __syncthreads();
  }
  if (i < NNODES) incl[i] = s[tid];
  if (tid == 255) blocksum[blockIdx.x] = s[255];
}

__global__ void scan_offsets(int* blocksum, int nb) {
  if (threadIdx.x == 0 && blockIdx.x == 0) {
    int run = 0;
    for (int b = 0; b < nb; ++b) { int t = blocksum[b]; blocksum[b] = run; run += t; }
  }
}

__global__ __launch_bounds__(256) void finalize_csr(const int* __restrict__ deg,
                                                    const int* __restrict__ incl,
                                                    const int* __restrict__ blocksum,
                                                    int* __restrict__ row_ptr) {
  int i = blockIdx.x * 256 + threadIdx.x;
  if (i >= NNODES) return;
  int tot = incl[i] + blocksum[i >> 8];
  row_ptr[i] = tot - deg[i];
  if (i == NNODES - 1) row_ptr[NNODES] = tot;
}

__global__ __launch_bounds__(1024) void bucket_csr(const uint2* __restrict__ stagingG,
                                                   const int* __restrict__ bucket_ptr,
                                                   const int* __restrict__ row_ptr,
                                                   int* __restrict__ colv) {
  __shared__ int cur[1024];
  int b = blockIdx.x, t = threadIdx.x;
  int n = (b << 10) + t;
  cur[t] = (n < NNODES) ? row_ptr[n] : 0;
  __syncthreads();
  int s0 = bucket_ptr[b], s1 = bucket_ptr[b + 1];
  for (int j = s0 + t; j < s1; j += 1024) {
    uint2 e = stagingG[j];
    int pos = atomicAdd(&cur[e.y & 1023], 1);
    colv[pos] = (int)e.x;
  }
}

// ---------------- tiered gather: compile-time lane idx -> readlane/SGPR ------
template<int T>
__device__ __forceinline__ void gather_T(const unsigned int* __restrict__ hwb,
                                         int lane, int sl, float w0l, float w1l,
                                         float& acc0, float& acc1) {
#pragma unroll
  for (int t = 0; t < T; ++t) {
    int s = __builtin_amdgcn_readlane(sl, t);                                   // SGPR
    float w0 = __uint_as_float(__builtin_amdgcn_readlane(__float_as_uint(w0l), t));
    float w1 = __uint_as_float(__builtin_amdgcn_readlane(__float_as_uint(w1l), t));
    unsigned q = hwb[(size_t)s * 64 + lane];   // saddr + lane offset
    acc0 = fmaf(w0, bf_lo(q), acc0);
    acc1 = fmaf(w1, bf_hi(q), acc1);
  }
}

// ---------------- softmax aggregation: one wave per dst node -----------------
__global__ __launch_bounds__(256) void aggregate(const unsigned int* __restrict__ hwb,
                                                 const float* __restrict__ a_s,
                                                 const float* __restrict__ a_d,
                                                 const int* __restrict__ row_ptr,
                                                 const int* __restrict__ colv,
                                                 const float* __restrict__ bias,
                                                 float* __restrict__ out) {
  int i = (blockIdx.x * 256 + threadIdx.x) >> 6;
  int lane = threadIdx.x & 63;
  if (i >= NNODES) return;
  float ad0 = a_d[2 * i], ad1 = a_d[2 * i + 1];
  float es0 = lrelu(a_s[2 * i] + ad0), es1 = lrelu(a_s[2 * i + 1] + ad1);  // self edge
  int start = row_ptr[i], end = row_ptr[i + 1];
  int deg = end - start;

  int sl = 0; float e0l = -1e30f, e1l = -1e30f;
  if (lane < deg) {
    sl = colv[start + lane];
    float2 av = *reinterpret_cast<const float2*>(&a_s[2 * sl]);
    e0l = lrelu(av.x + ad0); e1l = lrelu(av.y + ad1);
  }
  float m0 = fmaxf(es0, e0l), m1 = fmaxf(es1, e1l);
  for (int j = start + 64 + lane; j < end; j += 64) {
    int s = colv[j];
    float2 av = *reinterpret_cast<const float2*>(&a_s[2 * s]);
    m0 = fmaxf(m0, lrelu(av.x + ad0));
    m1 = fmaxf(m1, lrelu(av.y + ad1));
  }
  for (int o = 32; o; o >>= 1) {
    m0 = fmaxf(m0, __shfl_xor(m0, o));
    m1 = fmaxf(m1, __shfl_xor(m1, o));
  }
  float w0l = lane < deg ? __expf(e0l - m0) : 0.f;
  float w1l = lane < deg ? __expf(e1l - m1) : 0.f;
  float d0 = w0l, d1 = w1l;
  for (int o = 32; o; o >>= 1) { d0 += __shfl_xor(d0, o); d1 += __shfl_xor(d1, o); }
  float ws0 = __expf(es0 - m0), ws1 = __expf(es1 - m1);
  float den0 = d0 + ws0, den1 = d1 + ws1;

  unsigned int ps = hwb[(size_t)i * 64 + lane];
  float acc0 = ws0 * bf_lo(ps), acc1 = ws1 * bf_hi(ps);
  int dmin = deg < 64 ? deg : 64;
  // tiered fully-unrolled gather; ghost lanes carry sl=0, w=0 (hwb[0] is L1-hot)
  switch ((dmin + 7) >> 3) {
    case 1: gather_T<8 >(hwb, lane, sl, w0l, w1l, acc0, acc1); break;
    case 2: gather_T<16>(hwb, lane, sl, w0l, w1l, acc0, acc1); break;
    case 3: gather_T<24>(hwb, lane, sl, w0l, w1l, acc0, acc1); break;
    case 4: gather_T<32>(hwb, lane, sl, w0l, w1l, acc0, acc1); break;
    case 5: gather_T<40>(hwb, lane, sl, w0l, w1l, acc0, acc1); break;
    case 6: gather_T<48>(hwb, lane, sl, w0l, w1l, acc0, acc1); break;
    case 7: gather_T<56>(hwb, lane, sl, w0l, w1l, acc0, acc1); break;
    case 8: gather_T<64>(hwb, lane, sl, w0l, w1l, acc0, acc1); break;
    default: break;
  }
  for (int j = start + 64; j < end; ++j) {   // rare overflow path (deg > 64)
    int s = colv[j];
    float2 av = *reinterpret_cast<const float2*>(&a_s[2 * s]);
    float w0 = __expf(lrelu(av.x + ad0) - m0);
    float w1 = __expf(lrelu(av.y + ad1) - m1);
    den0 += w0; den1 += w1;
    unsigned int q = hwb[(size_t)s * 64 + lane];
    acc0 = fmaf(w0, bf_lo(q), acc0);
    acc1 = fmaf(w1, bf_hi(q), acc1);
  }
  out[(size_t)i * 128 + lane]      = fmaxf(acc0 / den0 + bias[lane], 0.f);
  out[(size_t)i * 128 + 64 + lane] = fmaxf(acc1 / den1 + bias[64 + lane], 0.f);
}

// ---------------- per-graph pooling, node-parallel ---------------------------
#define SEG_CHUNK 128
__global__ __launch_bounds__(128) void seg_sum_fast(const float* __restrict__ h,
                                                    const int* __restrict__ batch,
                                                    const int* __restrict__ gstart,
                                                    float* __restrict__ reprs) {
  int n0 = blockIdx.x * SEG_CHUNK;
  if (n0 >= NNODES) return;
  int nend = n0 + SEG_CHUNK; if (nend > NNODES) nend = NNODES;
  int tid = threadIdx.x;
  int r = n0;
  while (r < nend) {
    int g = batch[r];
    int segend = gstart[g + 1]; if (segend > nend) segend = nend;
    float a0 = 0.f, a1 = 0.f, a2 = 0.f, a3 = 0.f;
    for (; r + 3 < segend; r += 4) {
      a0 += h[(size_t)r * 128 + tid];
      a1 += h[(size_t)(r + 1) * 128 + tid];
      a2 += h[(size_t)(r + 2) * 128 + tid];
      a3 += h[(size_t)(r + 3) * 128 + tid];
    }
    for (; r < segend; ++r) a0 += h[(size_t)r * 128 + tid];
    atomicAdd(&reprs[g * 128 + tid], (a0 + a1) + (a2 + a3));
  }
}

// ---------------- head MLP + log_softmax -------------------------------------
__global__ __launch_bounds__(128) void head_kernel(const float* __restrict__ reprs,
                                                   const float* __restrict__ pw1,
                                                   const float* __restrict__ pb1,
                                                   const float* __restrict__ pw2,
                                                   const float* __restrict__ pb2,
                                                   float* __restrict__ out) {
  __shared__ float r[128], t1[128], z[NCLS];
  int g = blockIdx.x, tid = threadIdx.x;
  r[tid] = reprs[g * 128 + tid];
  __syncthreads();
  float acc = pb1[tid];
  for (int k = 0; k < 128; ++k) acc = fmaf(r[k], pw1[k * 128 + tid], acc);
  t1[tid] = fmaxf(acc, 0.f);
  __syncthreads();
  if (tid < NCLS) {
    float zz = pb2[tid];
    for (int k = 0; k < 128; ++k) zz = fmaf(t1[k], pw2[k * NCLS + tid], zz);
    z[tid] = zz;
  }
  __syncthreads();
  if (tid == 0) {
    float mx = -1e30f;
    for (int c = 0; c < NCLS; ++c) mx = fmaxf(mx, z[c]);
    float s = 0.f;
    for (int c = 0; c < NCLS; ++c) s += expf(z[c] - mx);
    float ls = logf(s) + mx;
    for (int c = 0; c < NCLS; ++c) out[g * NCLS + c] = z[c] - ls;
  }
}

extern "C" void kernel_launch(void* const* d_in, const int* in_sizes, int n_in,
                              void* d_out, int out_size, void* d_ws, size_t ws_size,
                              hipStream_t stream) {
  const float* x     = (const float*)d_in[0];
  const int*   eidx  = (const int*)d_in[1];
  const int*   batch = (const int*)d_in[2];
  const float* pre_w = (const float*)d_in[3];
  const float* pre_b = (const float*)d_in[4];
  const float* w1    = (const float*)d_in[5];
  const float* asrc1 = (const float*)d_in[6];
  const float* adst1 = (const float*)d_in[7];
  const float* b1    = (const float*)d_in[8];
  const float* w2    = (const float*)d_in[9];
  const float* asrc2 = (const float*)d_in[10];
  const float* adst2 = (const float*)d_in[11];
  const float* b2    = (const float*)d_in[12];
  const float* pw1   = (const float*)d_in[13];
  const float* pb1   = (const float*)d_in[14];
  const float* pw2   = (const float*)d_in[15];
  const float* pb2   = (const float*)d_in[16];
  float* out = (float*)d_out;

  const int* esrc = eidx;
  const int* edst = eidx + NEDGES;

  char* wsp = (char*)d_ws;
  size_t off = 0;
  auto alloc = [&](size_t bytes) -> void* {
    void* p = wsp + off;
    off += (bytes + 255) & ~(size_t)255;
    return p;
  };
  float* h          = (float*)alloc((size_t)NNODES * 128 * 4);
  unsigned int* hwb = (unsigned int*)alloc((size_t)NNODES * 64 * 4);
  float* a_s        = (float*)alloc((size_t)NNODES * 2 * 4);
  float* a_d        = (float*)alloc((size_t)NNODES * 2 * 4);
  float* reprs      = (float*)alloc((size_t)NGRAPH * 128 * 4);
  int* gstart       = (int*)alloc((NGRAPH + 1) * 4);
  int* deg          = (int*)alloc((size_t)NNODES * 4);
  int* incl         = (int*)alloc((size_t)NNODES * 4);
  int* row_ptr      = (int*)alloc(((size_t)NNODES + 1) * 4);
  int* colv         = (int*)alloc((size_t)NEDGES * 4);
  int* blocksum     = (int*)alloc(512 * 4);
  unsigned short* wt_pre = (unsigned short*)alloc((size_t)128 * FIN * 2);
  unsigned short* wt1    = (unsigned short*)alloc((size_t)128 * HDIM * 2);
  unsigned short* wt2    = (unsigned short*)alloc((size_t)128 * HDIM * 2);
  int* blockHist    = (int*)alloc((size_t)EBLK * NBUCK * 4);
  int* blockBaseCol = (int*)alloc((size_t)NBUCK * EBLK * 4);
  int* bucket_total = (int*)alloc(NBUCK * 4);
  int* bucket_ptr   = (int*)alloc((NBUCK + 1) * 4);
  uint2* stagingG   = (uint2*)alloc((size_t)NEDGES * 8);

  int nb = (NNODES + 255) / 256;   // 391
  int wb = NNODES / 4;             // wave-per-node kernels: 256 thr = 4 waves
  int sb = (NNODES + SEG_CHUNK - 1) / SEG_CHUNK;
  int gb = (NNODES + 127) / 128;   // 782 GEMM blocks

  // one-shot weight conversion (bf16, transposed)
  convert_transpose<<<(FIN * 128 + 255) / 256, 256, 0, stream>>>(pre_w, wt_pre, FIN);
  convert_transpose<<<(HDIM * 128 + 255) / 256, 256, 0, stream>>>(w1, wt1, HDIM);
  convert_transpose<<<(HDIM * 128 + 255) / 256, 256, 0, stream>>>(w2, wt2, HDIM);

  // graph boundaries + zeroed pooling accumulator
  hipMemsetAsync(reprs, 0, (size_t)NGRAPH * 128 * 4, stream);
  find_starts<<<1, 256, 0, stream>>>(batch, gstart);

  // bucketed CSR build
  bin_count<<<EBLK, 256, 0, stream>>>(edst, blockHist);
  colscan<<<NBUCK, 512, 0, stream>>>(blockHist, blockBaseCol, bucket_total);
  bscan<<<1, 128, 0, stream>>>(bucket_total, bucket_ptr);
  bin_place<<<EBLK, 512, 0, stream>>>(esrc, edst, blockBaseCol, bucket_ptr, stagingG);
  bucket_deg<<<NBUCK, 1024, 0, stream>>>(stagingG, bucket_ptr, deg);
  scan_block<<<nb, 256, 0, stream>>>(deg, incl, blocksum);
  scan_offsets<<<1, 64, 0, stream>>>(blocksum, nb);
  finalize_csr<<<nb, 256, 0, stream>>>(deg, incl, blocksum, row_ptr);
  bucket_csr<<<NBUCK, 1024, 0, stream>>>(stagingG, bucket_ptr, row_ptr, colv);

  // pre layer: h0 = relu(x @ pre_w + pre_b)
  gemm_mfma<<<gb, 256, 0, stream>>>(x, wt_pre, pre_b, h, nullptr,
                                    nullptr, nullptr, nullptr, nullptr, NNODES, FIN, 1);
  seg_sum_fast<<<sb, 128, 0, stream>>>(h, batch, gstart, reprs);

  // GAT layer 1 (alpha fused into GEMM epilogue)
  gemm_mfma<<<gb, 256, 0, stream>>>(h, wt1, nullptr, nullptr, hwb,
                                    asrc1, adst1, a_s, a_d, NNODES, HDIM, 0);
  aggregate<<<wb, 256, 0, stream>>>(hwb, a_s, a_d, row_ptr, colv, b1, h);
  seg_sum_fast<<<sb, 128, 0, stream>>>(h, batch, gstart, reprs);

  // GAT layer 2
  gemm_mfma<<<gb, 256, 0, stream>>>(h, wt2, nullptr, nullptr, hwb,
                                    asrc2, adst2, a_s, a_d, NNODES, HDIM, 0);
  aggregate<<<wb, 256, 0, stream>>>(hwb, a_s, a_d, row_ptr, colv, b2, h);
  seg_sum_fast<<<sb, 128, 0, stream>>>(h, batch, gstart, reprs);

  // head
  head_kernel<<<NGRAPH, 128, 0, stream>>>(reprs, pw1, pb1, pw2, pb2, out);
}